// Round 11
// baseline (661.056 us; speedup 1.0000x reference)
//
#include <hip/hip_runtime.h>

#define M_SZ 32768
#define N_SZ 4096
#define DEPTHS 4
#define SPLITK 8
#define KCH 512  // N_SZ / SPLITK

typedef __attribute__((ext_vector_type(8))) short bh8;   // 8 bf16 (4 VGPR) MFMA frag
typedef __attribute__((ext_vector_type(4))) float f4;    // MFMA accumulator
typedef unsigned short u16;
typedef unsigned int u32;

#define SBAR() __builtin_amdgcn_s_barrier()
#define FENCE() asm volatile("" ::: "memory")
#define WAITV(n) asm volatile("s_waitcnt vmcnt(" #n ")" ::: "memory")
#define WAITVL(n) asm volatile("s_waitcnt vmcnt(" #n ") lgkmcnt(0)" ::: "memory")

__device__ __forceinline__ u16 f2bf(float f) {
  u32 u = __float_as_uint(f);
  u = (u + 0x7FFFu + ((u >> 16) & 1u)) >> 16;  // RNE
  return (u16)u;
}

__device__ __forceinline__ float fast_tanh(float x) {
  float ax = __builtin_fabsf(x);
  float e = __builtin_exp2f(ax * 2.8853900817779268f);  // e^(2|x|)
  float r = 1.0f - 2.0f * __builtin_amdgcn_rcpf(e + 1.0f);
  return __builtin_copysignf(r, x);
}

__device__ __forceinline__ void async16(const void* g, void* l) {
  __builtin_amdgcn_global_load_lds((const __attribute__((address_space(1))) u32*)g,
                                   (__attribute__((address_space(3))) u32*)l, 16, 0, 0);
}

// ---------------------------------------------------------------------------
// K1: y_d[i][n] = sum_k s[n][k] * Wd[i][k]   (write TRANSPOSED [i][n], bf16)
// [R2-exact + counter zeroing for the k2a finisher]
// ---------------------------------------------------------------------------
__global__ void k1_kernel(const float* __restrict__ s, const float* __restrict__ Wd,
                          u16* __restrict__ Ytd, u32* __restrict__ cnt) {
  const int t = threadIdx.x;
  if (blockIdx.x == 0 && blockIdx.y == 0 && t < 32) cnt[t] = 0;
  const int n = blockIdx.x * 256 + t;
  const int i0 = blockIdx.y * 8;
  float acc[8] = {0.f, 0.f, 0.f, 0.f, 0.f, 0.f, 0.f, 0.f};
  const float4* srow = (const float4*)(s + (size_t)n * 128);
#pragma unroll 4
  for (int k4 = 0; k4 < 32; ++k4) {
    float4 sv = srow[k4];
#pragma unroll
    for (int ii = 0; ii < 8; ++ii) {
      const float* w = Wd + (i0 + ii) * 128 + k4 * 4;
      acc[ii] = fmaf(sv.x, w[0], acc[ii]);
      acc[ii] = fmaf(sv.y, w[1], acc[ii]);
      acc[ii] = fmaf(sv.z, w[2], acc[ii]);
      acc[ii] = fmaf(sv.w, w[3], acc[ii]);
    }
  }
#pragma unroll
  for (int ii = 0; ii < 8; ++ii)
    Ytd[(size_t)(i0 + ii) * 4096 + n] = f2bf(acc[ii]);
}

// ---------------------------------------------------------------------------
// K2a: split-K partials of self_kernel @ y_d  [R2-exact GEMM core] + fused
// deterministic last-block finisher (R4/R5-proven pattern): fixed-order
// c-sum + bias + tanh -> s_out.  Replaces the separate k2b launch and the
// d2d memcpy (depth 0 reads self_act via s_src).
// ---------------------------------------------------------------------------
__global__ __launch_bounds__(512, 2) void k2a_kernel(
    const float* __restrict__ SK, const u16* __restrict__ Ytd, float* __restrict__ Zp,
    const float* __restrict__ s_src, float* __restrict__ s_out,
    const float* __restrict__ bd, u32* __restrict__ cnt) {
  __shared__ char smem[8192 + 2 * 8192];
  __shared__ u32 lastFlag;
  char* sA = smem;
  char* sB0 = smem + 8192;
  char* sB1 = smem + 8192 + 8192;
  const int t = threadIdx.x, lane = t & 63, wid = t >> 6;
  const int wr = wid >> 2, wc = wid & 3;
  const int n0 = blockIdx.x * 128;
  const int kbase = blockIdx.y * KCH;

  const int arow = t >> 2, kseg = t & 3;
  const float4* ag = (const float4*)(SK + (size_t)(n0 + arow) * 4096 + kbase + kseg * 8);
  const int awoff = arow * 64 + ((kseg ^ (arow & 3)) << 4);

  const int P = wid * 64 + lane;
  const int bcol = P >> 2;
  const int bg = (P & 3) ^ (bcol & 3);
  const u16* bsrc = Ytd + (size_t)bcol * 4096 + kbase + bg * 8;
  const int bldst = wid * 1024;  // wave-uniform

  const int l15 = lane & 15, l4 = lane >> 4;
  int aro[4], bro[2];
#pragma unroll
  for (int mf = 0; mf < 4; ++mf) {
    int row = wr * 64 + mf * 16 + l15;
    aro[mf] = row * 64 + ((l4 ^ (row & 3)) << 4);
  }
#pragma unroll
  for (int n2 = 0; n2 < 2; ++n2) {
    int col = wc * 32 + n2 * 16 + l15;
    bro[n2] = col * 64 + ((l4 ^ (col & 3)) << 4);
  }

  f4 acc[4][2];
#pragma unroll
  for (int i = 0; i < 4; ++i)
#pragma unroll
    for (int j = 0; j < 2; ++j) acc[i][j] = (f4){0.f, 0.f, 0.f, 0.f};

  float4 va0 = ag[0], va1 = ag[1];
  FENCE();
  async16(bsrc, sB0 + bldst);
  FENCE();

  char* sBc = sB0;
  char* sBn = sB1;
  for (int k = 0; k < 15; ++k) {
    SBAR(); FENCE();
    WAITV(1);
    union { bh8 v; u16 u[8]; } p;
    p.u[0] = f2bf(va0.x); p.u[1] = f2bf(va0.y); p.u[2] = f2bf(va0.z); p.u[3] = f2bf(va0.w);
    p.u[4] = f2bf(va1.x); p.u[5] = f2bf(va1.y); p.u[6] = f2bf(va1.z); p.u[7] = f2bf(va1.w);
    *(bh8*)(sA + awoff) = p.v;
    FENCE();
    va0 = ag[(k + 1) * 8]; va1 = ag[(k + 1) * 8 + 1];
    FENCE();
    WAITVL(2);
    SBAR(); FENCE();
    async16(bsrc + (k + 1) * 32, sBn + bldst);
    FENCE();
    bh8 af[4];
#pragma unroll
    for (int mf = 0; mf < 4; ++mf) af[mf] = *(const bh8*)(sA + aro[mf]);
#pragma unroll
    for (int n2 = 0; n2 < 2; ++n2) {
      bh8 b = *(const bh8*)(sBc + bro[n2]);
#pragma unroll
      for (int mf = 0; mf < 4; ++mf)
        acc[mf][n2] = __builtin_amdgcn_mfma_f32_16x16x32_bf16(af[mf], b, acc[mf][n2], 0, 0, 0);
    }
    char* tp = sBc; sBc = sBn; sBn = tp;
  }
  SBAR(); FENCE();
  WAITV(1);
  {
    union { bh8 v; u16 u[8]; } p;
    p.u[0] = f2bf(va0.x); p.u[1] = f2bf(va0.y); p.u[2] = f2bf(va0.z); p.u[3] = f2bf(va0.w);
    p.u[4] = f2bf(va1.x); p.u[5] = f2bf(va1.y); p.u[6] = f2bf(va1.z); p.u[7] = f2bf(va1.w);
    *(bh8*)(sA + awoff) = p.v;
  }
  WAITVL(0);
  SBAR(); FENCE();
  {
    bh8 af[4];
#pragma unroll
    for (int mf = 0; mf < 4; ++mf) af[mf] = *(const bh8*)(sA + aro[mf]);
#pragma unroll
    for (int n2 = 0; n2 < 2; ++n2) {
      bh8 b = *(const bh8*)(sBc + bro[n2]);
#pragma unroll
      for (int mf = 0; mf < 4; ++mf)
        acc[mf][n2] = __builtin_amdgcn_mfma_f32_16x16x32_bf16(af[mf], b, acc[mf][n2], 0, 0, 0);
    }
  }

  float* Z = Zp + (size_t)blockIdx.y * (N_SZ * 128) + (size_t)n0 * 128;
#pragma unroll
  for (int mf = 0; mf < 4; ++mf)
#pragma unroll
    for (int n2 = 0; n2 < 2; ++n2)
#pragma unroll
      for (int q = 0; q < 4; ++q) {
        int r = wr * 64 + mf * 16 + l4 * 4 + q;
        int c = wc * 32 + n2 * 16 + l15;
        Z[r * 128 + c] = acc[mf][n2][q];
      }

  // deterministic last-block finisher (fixed-order sum over c partials)
  __threadfence();
  __syncthreads();
  if (t == 0) lastFlag = (atomicAdd(&cnt[blockIdx.x], 1) == SPLITK - 1) ? 1u : 0u;
  __syncthreads();
  if (lastFlag) {
    __threadfence();
    for (int idx = t; idx < 128 * 128; idx += 512) {
      int r = idx >> 7, ccol = idx & 127;
      size_t gi = (size_t)(n0 + r) * 128 + ccol;
      float v = bd[ccol];
#pragma unroll
      for (int cc = 0; cc < SPLITK; ++cc) v += Zp[(size_t)cc * (N_SZ * 128) + gi];
      s_out[gi] = s_src[gi] + fast_tanh(v);
    }
  }
}

// ---------------------------------------------------------------------------
// phaseB v6b: out = act + sum_d tanh(kern @ y_d + b_d).  [R10-exact, frozen]
// grid 256, block 1024 (16 waves = 4/SIMD intra-block TLP). Tile 128r x
// 512tc, K-step 32, 128 iters. wr = wid>>3, wc = wid&7; acc[4 mf][4 d].
// ---------------------------------------------------------------------------
__global__ __launch_bounds__(1024, 4) void pB_kernel(
    const float* __restrict__ A, const u16* __restrict__ Yt,
    const float* __restrict__ act, const float* __restrict__ bias,
    float* __restrict__ outA) {
  __shared__ char smem[8192 + 2 * 32768];
  char* sA = smem;
  char* sB0 = smem + 8192;
  char* sB1 = smem + 8192 + 32768;
  const int t = threadIdx.x, lane = t & 63, wid = t >> 6;
  const int wr = wid >> 3, wc = wid & 7;
  const int m0 = blockIdx.x * 128;
  const int l15 = lane & 15, l4 = lane >> 4;

  const int arow = t >> 3, aseg = t & 7;
  const float4* agp = (const float4*)(A + (size_t)(m0 + arow) * 4096 + aseg * 4);
  const int awoff = arow * 64 + (((aseg >> 1) ^ (arow & 3)) << 4) + ((aseg & 1) << 3);

  const u16* bsrc[2];
  int bldst[2];
#pragma unroll
  for (int j = 0; j < 2; ++j) {
    int G = j * 1024 + t;
    int col = G >> 2;
    int g = (G & 3) ^ (col & 3);
    bsrc[j] = Yt + (size_t)col * 4096 + g * 8;
    bldst[j] = (j * 16 + wid) * 1024;  // wave-uniform base (+ lane*16 by HW)
  }

  int aro[4], bro[4];
#pragma unroll
  for (int mf = 0; mf < 4; ++mf) {
    int row = wr * 64 + mf * 16 + l15;  // in [0,128) exactly once over (wr,mf)
    aro[mf] = row * 64 + ((l4 ^ (row & 3)) << 4);
  }
#pragma unroll
  for (int d = 0; d < 4; ++d) {
    int tc = d * 128 + wc * 16 + l15;   // in [0,512)
    bro[d] = tc * 64 + ((l4 ^ (tc & 3)) << 4);
  }

  f4 acc[4][4];  // [mf][d]
#pragma unroll
  for (int i = 0; i < 4; ++i)
#pragma unroll
    for (int j = 0; j < 4; ++j) acc[i][j] = (f4){0.f, 0.f, 0.f, 0.f};

  float4 va = agp[0];
  FENCE();
  async16(bsrc[0], sB0 + bldst[0]);
  async16(bsrc[1], sB0 + bldst[1]);
  FENCE();

  char* sBc = sB0;
  char* sBn = sB1;
#pragma unroll 1
  for (int k = 0; k < 127; ++k) {
    SBAR(); FENCE();
    WAITV(2);  // retire A(k); B(k) x2 may fly
    union { uint2 v; u16 u[4]; } p;
    p.u[0] = f2bf(va.x); p.u[1] = f2bf(va.y); p.u[2] = f2bf(va.z); p.u[3] = f2bf(va.w);
    *(uint2*)(sA + awoff) = p.v;
    FENCE();
    va = agp[(k + 1) * 8];  // issue A(k+1)
    FENCE();
    WAITVL(1);  // retire B(k) x2; A(k+1) stays in flight
    SBAR(); FENCE();
    async16(bsrc[0] + (k + 1) * 32, sBn + bldst[0]);
    async16(bsrc[1] + (k + 1) * 32, sBn + bldst[1]);
    FENCE();
    bh8 af[4];
#pragma unroll
    for (int mf = 0; mf < 4; ++mf) af[mf] = *(const bh8*)(sA + aro[mf]);
#pragma unroll
    for (int d = 0; d < 4; ++d) {
      bh8 b = *(const bh8*)(sBc + bro[d]);
#pragma unroll
      for (int mf = 0; mf < 4; ++mf)
        acc[mf][d] = __builtin_amdgcn_mfma_f32_16x16x32_bf16(af[mf], b, acc[mf][d], 0, 0, 0);
    }
    char* tp = sBc; sBc = sBn; sBn = tp;
  }
  SBAR(); FENCE();
  WAITV(2);
  {
    union { uint2 v; u16 u[4]; } p;
    p.u[0] = f2bf(va.x); p.u[1] = f2bf(va.y); p.u[2] = f2bf(va.z); p.u[3] = f2bf(va.w);
    *(uint2*)(sA + awoff) = p.v;
  }
  WAITVL(0);
  SBAR(); FENCE();
  {
    bh8 af[4];
#pragma unroll
    for (int mf = 0; mf < 4; ++mf) af[mf] = *(const bh8*)(sA + aro[mf]);
#pragma unroll
    for (int d = 0; d < 4; ++d) {
      bh8 b = *(const bh8*)(sBc + bro[d]);
#pragma unroll
      for (int mf = 0; mf < 4; ++mf)
        acc[mf][d] = __builtin_amdgcn_mfma_f32_16x16x32_bf16(af[mf], b, acc[mf][d], 0, 0, 0);
    }
  }

  float bsv[4];
#pragma unroll
  for (int d = 0; d < 4; ++d) bsv[d] = bias[d * 128 + wc * 16 + l15];
#pragma unroll
  for (int mf = 0; mf < 4; ++mf)
#pragma unroll
    for (int q = 0; q < 4; ++q) {
      int r = m0 + wr * 64 + mf * 16 + l4 * 4 + q;
      int c = wc * 16 + l15;
      float s = 0.f;
#pragma unroll
      for (int d = 0; d < 4; ++d) s += fast_tanh(acc[mf][d][q] + bsv[d]);
      size_t o = (size_t)r * 128 + c;
      outA[o] = act[o] + s;
    }
}

// ---------------------------------------------------------------------------
extern "C" void kernel_launch(void* const* d_in, const int* in_sizes, int n_in,
                              void* d_out, int out_size, void* d_ws, size_t ws_size,
                              hipStream_t stream) {
  const float* act = (const float*)d_in[0];
  const float* self_act = (const float*)d_in[1];
  const float* kern = (const float*)d_in[2];
  const float* self_kern = (const float*)d_in[3];
  const float* weights = (const float*)d_in[4];
  const float* bias = (const float*)d_in[5];
  float* out = (float*)d_out;
  float* s_buf = out + (size_t)M_SZ * 128;  // self_act state lives in its output slot

  char* ws = (char*)d_ws;
  u16* Yt = (u16*)ws;                          // [512][4096] bf16, 4 MB
  float* Zp = (float*)(ws + (4u << 20));       // [SPLITK][4096][128] f32, 16 MB
  u32* counters = (u32*)(ws + (20u << 20));    // [32]

  for (int d = 0; d < DEPTHS; ++d) {
    const float* s_src = (d == 0) ? self_act : s_buf;
    k1_kernel<<<dim3(16, 16), 256, 0, stream>>>(s_src, weights + d * 16384,
                                                Yt + (size_t)d * 128 * 4096, counters);
    k2a_kernel<<<dim3(32, SPLITK), 512, 0, stream>>>(self_kern,
                                                     Yt + (size_t)d * 128 * 4096, Zp,
                                                     s_src, s_buf, bias + d * 128,
                                                     counters);
  }
  pB_kernel<<<256, 1024, 0, stream>>>(kern, Yt, act, bias, out);
}

// Round 12
// 386.252 us; speedup vs baseline: 1.7115x; 1.7115x over previous
//
#include <hip/hip_runtime.h>

#define M_SZ 32768
#define N_SZ 4096
#define DEPTHS 4
#define SPLITK 16
#define KCH 256  // N_SZ / SPLITK

typedef __attribute__((ext_vector_type(8))) short bh8;   // 8 bf16 (4 VGPR) MFMA frag
typedef __attribute__((ext_vector_type(4))) float f4;    // MFMA accumulator
typedef unsigned short u16;
typedef unsigned int u32;

#define SBAR() __builtin_amdgcn_s_barrier()
#define FENCE() asm volatile("" ::: "memory")
#define WAITV(n) asm volatile("s_waitcnt vmcnt(" #n ")" ::: "memory")
#define WAITVL(n) asm volatile("s_waitcnt vmcnt(" #n ") lgkmcnt(0)" ::: "memory")

__device__ __forceinline__ u16 f2bf(float f) {
  u32 u = __float_as_uint(f);
  u = (u + 0x7FFFu + ((u >> 16) & 1u)) >> 16;  // RNE
  return (u16)u;
}

__device__ __forceinline__ float fast_tanh(float x) {
  float ax = __builtin_fabsf(x);
  float e = __builtin_exp2f(ax * 2.8853900817779268f);  // e^(2|x|)
  float r = 1.0f - 2.0f * __builtin_amdgcn_rcpf(e + 1.0f);
  return __builtin_copysignf(r, x);
}

__device__ __forceinline__ void async16(const void* g, void* l) {
  __builtin_amdgcn_global_load_lds((const __attribute__((address_space(1))) u32*)g,
                                   (__attribute__((address_space(3))) u32*)l, 16, 0, 0);
}

// ---------------------------------------------------------------------------
// K1: y_d[i][n] = sum_k s[n][k] * Wd[i][k]   (write TRANSPOSED [i][n], bf16)
// [R10-exact]
// ---------------------------------------------------------------------------
__global__ void k1_kernel(const float* __restrict__ s, const float* __restrict__ Wd,
                          u16* __restrict__ Ytd) {
  const int n = blockIdx.x * 256 + threadIdx.x;
  const int i0 = blockIdx.y * 8;
  float acc[8] = {0.f, 0.f, 0.f, 0.f, 0.f, 0.f, 0.f, 0.f};
  const float4* srow = (const float4*)(s + (size_t)n * 128);
#pragma unroll 4
  for (int k4 = 0; k4 < 32; ++k4) {
    float4 sv = srow[k4];
#pragma unroll
    for (int ii = 0; ii < 8; ++ii) {
      const float* w = Wd + (i0 + ii) * 128 + k4 * 4;
      acc[ii] = fmaf(sv.x, w[0], acc[ii]);
      acc[ii] = fmaf(sv.y, w[1], acc[ii]);
      acc[ii] = fmaf(sv.z, w[2], acc[ii]);
      acc[ii] = fmaf(sv.w, w[3], acc[ii]);
    }
  }
#pragma unroll
  for (int ii = 0; ii < 8; ++ii)
    Ytd[(size_t)(i0 + ii) * 4096 + n] = f2bf(acc[ii]);
}

// ---------------------------------------------------------------------------
// K2a: split-K partials of self_kernel @ y_d. [R10 GEMM core; SPLITK 8->16 so
// grid (32,16) = 512 blocks = 2 blocks/CU = 4 waves/SIMD -- the R10 pB
// mechanism applied to the prologue. 8 K-iters, KCH 256.]
// ---------------------------------------------------------------------------
__global__ __launch_bounds__(512, 2) void k2a_kernel(
    const float* __restrict__ SK, const u16* __restrict__ Ytd, float* __restrict__ Zp) {
  __shared__ char smem[8192 + 2 * 8192];
  char* sA = smem;
  char* sB0 = smem + 8192;
  char* sB1 = smem + 8192 + 8192;
  const int t = threadIdx.x, lane = t & 63, wid = t >> 6;
  const int wr = wid >> 2, wc = wid & 3;
  const int n0 = blockIdx.x * 128;
  const int kbase = blockIdx.y * KCH;

  const int arow = t >> 2, kseg = t & 3;
  const float4* ag = (const float4*)(SK + (size_t)(n0 + arow) * 4096 + kbase + kseg * 8);
  const int awoff = arow * 64 + ((kseg ^ (arow & 3)) << 4);

  const int P = wid * 64 + lane;
  const int bcol = P >> 2;
  const int bg = (P & 3) ^ (bcol & 3);
  const u16* bsrc = Ytd + (size_t)bcol * 4096 + kbase + bg * 8;
  const int bldst = wid * 1024;  // wave-uniform

  const int l15 = lane & 15, l4 = lane >> 4;
  int aro[4], bro[2];
#pragma unroll
  for (int mf = 0; mf < 4; ++mf) {
    int row = wr * 64 + mf * 16 + l15;
    aro[mf] = row * 64 + ((l4 ^ (row & 3)) << 4);
  }
#pragma unroll
  for (int n2 = 0; n2 < 2; ++n2) {
    int col = wc * 32 + n2 * 16 + l15;
    bro[n2] = col * 64 + ((l4 ^ (col & 3)) << 4);
  }

  f4 acc[4][2];
#pragma unroll
  for (int i = 0; i < 4; ++i)
#pragma unroll
    for (int j = 0; j < 2; ++j) acc[i][j] = (f4){0.f, 0.f, 0.f, 0.f};

  float4 va0 = ag[0], va1 = ag[1];
  FENCE();
  async16(bsrc, sB0 + bldst);
  FENCE();

  char* sBc = sB0;
  char* sBn = sB1;
  for (int k = 0; k < 7; ++k) {
    SBAR(); FENCE();
    WAITV(1);
    union { bh8 v; u16 u[8]; } p;
    p.u[0] = f2bf(va0.x); p.u[1] = f2bf(va0.y); p.u[2] = f2bf(va0.z); p.u[3] = f2bf(va0.w);
    p.u[4] = f2bf(va1.x); p.u[5] = f2bf(va1.y); p.u[6] = f2bf(va1.z); p.u[7] = f2bf(va1.w);
    *(bh8*)(sA + awoff) = p.v;
    FENCE();
    va0 = ag[(k + 1) * 8]; va1 = ag[(k + 1) * 8 + 1];
    FENCE();
    WAITVL(2);
    SBAR(); FENCE();
    async16(bsrc + (k + 1) * 32, sBn + bldst);
    FENCE();
    bh8 af[4];
#pragma unroll
    for (int mf = 0; mf < 4; ++mf) af[mf] = *(const bh8*)(sA + aro[mf]);
#pragma unroll
    for (int n2 = 0; n2 < 2; ++n2) {
      bh8 b = *(const bh8*)(sBc + bro[n2]);
#pragma unroll
      for (int mf = 0; mf < 4; ++mf)
        acc[mf][n2] = __builtin_amdgcn_mfma_f32_16x16x32_bf16(af[mf], b, acc[mf][n2], 0, 0, 0);
    }
    char* tp = sBc; sBc = sBn; sBn = tp;
  }
  SBAR(); FENCE();
  WAITV(1);
  {
    union { bh8 v; u16 u[8]; } p;
    p.u[0] = f2bf(va0.x); p.u[1] = f2bf(va0.y); p.u[2] = f2bf(va0.z); p.u[3] = f2bf(va0.w);
    p.u[4] = f2bf(va1.x); p.u[5] = f2bf(va1.y); p.u[6] = f2bf(va1.z); p.u[7] = f2bf(va1.w);
    *(bh8*)(sA + awoff) = p.v;
  }
  WAITVL(0);
  SBAR(); FENCE();
  {
    bh8 af[4];
#pragma unroll
    for (int mf = 0; mf < 4; ++mf) af[mf] = *(const bh8*)(sA + aro[mf]);
#pragma unroll
    for (int n2 = 0; n2 < 2; ++n2) {
      bh8 b = *(const bh8*)(sBc + bro[n2]);
#pragma unroll
      for (int mf = 0; mf < 4; ++mf)
        acc[mf][n2] = __builtin_amdgcn_mfma_f32_16x16x32_bf16(af[mf], b, acc[mf][n2], 0, 0, 0);
    }
  }

  float* Z = Zp + (size_t)blockIdx.y * (N_SZ * 128) + (size_t)n0 * 128;
#pragma unroll
  for (int mf = 0; mf < 4; ++mf)
#pragma unroll
    for (int n2 = 0; n2 < 2; ++n2)
#pragma unroll
      for (int q = 0; q < 4; ++q) {
        int r = wr * 64 + mf * 16 + l4 * 4 + q;
        int c = wc * 32 + n2 * 16 + l15;
        Z[r * 128 + c] = acc[mf][n2][q];
      }
}

// ---------------------------------------------------------------------------
// K2b: s[n][i] += tanh(sum_c Zp[c][n][i] + b[i])  [R10-exact; 16 chunks]
// ---------------------------------------------------------------------------
__global__ void k2b_kernel(float* __restrict__ s, const float* __restrict__ Zp,
                           const float* __restrict__ bd) {
  int idx = blockIdx.x * 256 + threadIdx.x;
  float v = bd[idx & 127];
#pragma unroll
  for (int c = 0; c < SPLITK; ++c) v += Zp[(size_t)c * (N_SZ * 128) + idx];
  s[idx] += fast_tanh(v);
}

// ---------------------------------------------------------------------------
// phaseB v6b: out = act + sum_d tanh(kern @ y_d + b_d).  [R10-exact, frozen]
// grid 256, block 1024 (16 waves = 4/SIMD intra-block TLP). Tile 128r x
// 512tc, K-step 32, 128 iters. wr = wid>>3, wc = wid&7; acc[4 mf][4 d].
// ---------------------------------------------------------------------------
__global__ __launch_bounds__(1024, 4) void pB_kernel(
    const float* __restrict__ A, const u16* __restrict__ Yt,
    const float* __restrict__ act, const float* __restrict__ bias,
    float* __restrict__ outA) {
  __shared__ char smem[8192 + 2 * 32768];
  char* sA = smem;
  char* sB0 = smem + 8192;
  char* sB1 = smem + 8192 + 32768;
  const int t = threadIdx.x, lane = t & 63, wid = t >> 6;
  const int wr = wid >> 3, wc = wid & 7;
  const int m0 = blockIdx.x * 128;
  const int l15 = lane & 15, l4 = lane >> 4;

  const int arow = t >> 3, aseg = t & 7;
  const float4* agp = (const float4*)(A + (size_t)(m0 + arow) * 4096 + aseg * 4);
  const int awoff = arow * 64 + (((aseg >> 1) ^ (arow & 3)) << 4) + ((aseg & 1) << 3);

  const u16* bsrc[2];
  int bldst[2];
#pragma unroll
  for (int j = 0; j < 2; ++j) {
    int G = j * 1024 + t;
    int col = G >> 2;
    int g = (G & 3) ^ (col & 3);
    bsrc[j] = Yt + (size_t)col * 4096 + g * 8;
    bldst[j] = (j * 16 + wid) * 1024;  // wave-uniform base (+ lane*16 by HW)
  }

  int aro[4], bro[4];
#pragma unroll
  for (int mf = 0; mf < 4; ++mf) {
    int row = wr * 64 + mf * 16 + l15;  // in [0,128) exactly once over (wr,mf)
    aro[mf] = row * 64 + ((l4 ^ (row & 3)) << 4);
  }
#pragma unroll
  for (int d = 0; d < 4; ++d) {
    int tc = d * 128 + wc * 16 + l15;   // in [0,512)
    bro[d] = tc * 64 + ((l4 ^ (tc & 3)) << 4);
  }

  f4 acc[4][4];  // [mf][d]
#pragma unroll
  for (int i = 0; i < 4; ++i)
#pragma unroll
    for (int j = 0; j < 4; ++j) acc[i][j] = (f4){0.f, 0.f, 0.f, 0.f};

  float4 va = agp[0];
  FENCE();
  async16(bsrc[0], sB0 + bldst[0]);
  async16(bsrc[1], sB0 + bldst[1]);
  FENCE();

  char* sBc = sB0;
  char* sBn = sB1;
#pragma unroll 1
  for (int k = 0; k < 127; ++k) {
    SBAR(); FENCE();
    WAITV(2);  // retire A(k); B(k) x2 may fly
    union { uint2 v; u16 u[4]; } p;
    p.u[0] = f2bf(va.x); p.u[1] = f2bf(va.y); p.u[2] = f2bf(va.z); p.u[3] = f2bf(va.w);
    *(uint2*)(sA + awoff) = p.v;
    FENCE();
    va = agp[(k + 1) * 8];  // issue A(k+1)
    FENCE();
    WAITVL(1);  // retire B(k) x2; A(k+1) stays in flight
    SBAR(); FENCE();
    async16(bsrc[0] + (k + 1) * 32, sBn + bldst[0]);
    async16(bsrc[1] + (k + 1) * 32, sBn + bldst[1]);
    FENCE();
    bh8 af[4];
#pragma unroll
    for (int mf = 0; mf < 4; ++mf) af[mf] = *(const bh8*)(sA + aro[mf]);
#pragma unroll
    for (int d = 0; d < 4; ++d) {
      bh8 b = *(const bh8*)(sBc + bro[d]);
#pragma unroll
      for (int mf = 0; mf < 4; ++mf)
        acc[mf][d] = __builtin_amdgcn_mfma_f32_16x16x32_bf16(af[mf], b, acc[mf][d], 0, 0, 0);
    }
    char* tp = sBc; sBc = sBn; sBn = tp;
  }
  SBAR(); FENCE();
  WAITV(2);
  {
    union { uint2 v; u16 u[4]; } p;
    p.u[0] = f2bf(va.x); p.u[1] = f2bf(va.y); p.u[2] = f2bf(va.z); p.u[3] = f2bf(va.w);
    *(uint2*)(sA + awoff) = p.v;
  }
  WAITVL(0);
  SBAR(); FENCE();
  {
    bh8 af[4];
#pragma unroll
    for (int mf = 0; mf < 4; ++mf) af[mf] = *(const bh8*)(sA + aro[mf]);
#pragma unroll
    for (int d = 0; d < 4; ++d) {
      bh8 b = *(const bh8*)(sBc + bro[d]);
#pragma unroll
      for (int mf = 0; mf < 4; ++mf)
        acc[mf][d] = __builtin_amdgcn_mfma_f32_16x16x32_bf16(af[mf], b, acc[mf][d], 0, 0, 0);
    }
  }

  float bsv[4];
#pragma unroll
  for (int d = 0; d < 4; ++d) bsv[d] = bias[d * 128 + wc * 16 + l15];
#pragma unroll
  for (int mf = 0; mf < 4; ++mf)
#pragma unroll
    for (int q = 0; q < 4; ++q) {
      int r = m0 + wr * 64 + mf * 16 + l4 * 4 + q;
      int c = wc * 16 + l15;
      float s = 0.f;
#pragma unroll
      for (int d = 0; d < 4; ++d) s += fast_tanh(acc[mf][d][q] + bsv[d]);
      size_t o = (size_t)r * 128 + c;
      outA[o] = act[o] + s;
    }
}

// ---------------------------------------------------------------------------
extern "C" void kernel_launch(void* const* d_in, const int* in_sizes, int n_in,
                              void* d_out, int out_size, void* d_ws, size_t ws_size,
                              hipStream_t stream) {
  const float* act = (const float*)d_in[0];
  const float* self_act = (const float*)d_in[1];
  const float* kern = (const float*)d_in[2];
  const float* self_kern = (const float*)d_in[3];
  const float* weights = (const float*)d_in[4];
  const float* bias = (const float*)d_in[5];
  float* out = (float*)d_out;
  float* s_buf = out + (size_t)M_SZ * 128;  // self_act state lives in its output slot

  char* ws = (char*)d_ws;
  u16* Yt = (u16*)ws;                          // [512][4096] bf16, 4 MB
  float* Zp = (float*)(ws + (4u << 20));       // [SPLITK][4096][128] f32, 32 MB

  hipMemcpyAsync(s_buf, self_act, (size_t)N_SZ * 128 * sizeof(float),
                 hipMemcpyDeviceToDevice, stream);

  for (int d = 0; d < DEPTHS; ++d) {
    k1_kernel<<<dim3(16, 16), 256, 0, stream>>>(s_buf, weights + d * 16384,
                                                Yt + (size_t)d * 128 * 4096);
    k2a_kernel<<<dim3(32, SPLITK), 512, 0, stream>>>(self_kern,
                                                     Yt + (size_t)d * 128 * 4096, Zp);
    k2b_kernel<<<2048, 256, 0, stream>>>(s_buf, Zp, bias + d * 128);
  }
  pB_kernel<<<256, 1024, 0, stream>>>(kern, Yt, act, bias, out);
}

// Round 13
// 365.873 us; speedup vs baseline: 1.8068x; 1.0557x over previous
//
#include <hip/hip_runtime.h>

#define M_SZ 32768
#define N_SZ 4096
#define DEPTHS 4
#define SPLITK 8
#define KCH 512  // N_SZ / SPLITK

typedef __attribute__((ext_vector_type(8))) short bh8;   // 8 bf16 (4 VGPR) MFMA frag
typedef __attribute__((ext_vector_type(4))) float f4;    // MFMA accumulator
typedef unsigned short u16;
typedef unsigned int u32;

#define SBAR() __builtin_amdgcn_s_barrier()
#define FENCE() asm volatile("" ::: "memory")
#define WAITV(n) asm volatile("s_waitcnt vmcnt(" #n ")" ::: "memory")
#define WAITVL(n) asm volatile("s_waitcnt vmcnt(" #n ") lgkmcnt(0)" ::: "memory")

__device__ __forceinline__ u16 f2bf(float f) {
  u32 u = __float_as_uint(f);
  u = (u + 0x7FFFu + ((u >> 16) & 1u)) >> 16;  // RNE
  return (u16)u;
}

__device__ __forceinline__ float fast_tanh(float x) {
  float ax = __builtin_fabsf(x);
  float e = __builtin_exp2f(ax * 2.8853900817779268f);  // e^(2|x|)
  float r = 1.0f - 2.0f * __builtin_amdgcn_rcpf(e + 1.0f);
  return __builtin_copysignf(r, x);
}

__device__ __forceinline__ void async16(const void* g, void* l) {
  __builtin_amdgcn_global_load_lds((const __attribute__((address_space(1))) u32*)g,
                                   (__attribute__((address_space(3))) u32*)l, 16, 0, 0);
}

// ---------------------------------------------------------------------------
// K1: y_d[i][n] = sum_k s[n][k] * Wd[i][k]   (write TRANSPOSED [i][n], bf16)
// [R10-exact; s passed explicitly so depth 0 reads self_act -- no memcpy]
// ---------------------------------------------------------------------------
__global__ void k1_kernel(const float* __restrict__ s, const float* __restrict__ Wd,
                          u16* __restrict__ Ytd) {
  const int n = blockIdx.x * 256 + threadIdx.x;
  const int i0 = blockIdx.y * 8;
  float acc[8] = {0.f, 0.f, 0.f, 0.f, 0.f, 0.f, 0.f, 0.f};
  const float4* srow = (const float4*)(s + (size_t)n * 128);
#pragma unroll 4
  for (int k4 = 0; k4 < 32; ++k4) {
    float4 sv = srow[k4];
#pragma unroll
    for (int ii = 0; ii < 8; ++ii) {
      const float* w = Wd + (i0 + ii) * 128 + k4 * 4;
      acc[ii] = fmaf(sv.x, w[0], acc[ii]);
      acc[ii] = fmaf(sv.y, w[1], acc[ii]);
      acc[ii] = fmaf(sv.z, w[2], acc[ii]);
      acc[ii] = fmaf(sv.w, w[3], acc[ii]);
    }
  }
#pragma unroll
  for (int ii = 0; ii < 8; ++ii)
    Ytd[(size_t)(i0 + ii) * 4096 + n] = f2bf(acc[ii]);
}

// ---------------------------------------------------------------------------
// K2a64: split-K partials of self_kernel @ y_d.  R3 z-phase geometry (proven
// numerics + zero bank conflicts): tile 64n x 128i, K-step 64, grid (64,8) =
// 512 blocks = 2 blocks/CU = 4 waves/SIMD at CONSTANT Zp traffic (the R10 pB
// TLP mechanism; R12's split-K version paid 2x traffic, this doesn't).
// 8 waves: wr=wid>>1 (4) x wc=wid&1 (2); wave 16n x 64i; acc 16 f32.
// VGPR ~80 <= 128 cap from launch_bounds(512,4). LDS 40KB -> 2 blocks/CU.
// ---------------------------------------------------------------------------
__global__ __launch_bounds__(512, 4) void k2a_kernel(
    const float* __restrict__ SK, const u16* __restrict__ Ytd, float* __restrict__ Zp) {
  __shared__ char smem[8192 + 2 * 16384];
  char* sA = smem;
  char* sB0 = smem + 8192;
  char* sB1 = smem + 8192 + 16384;
  const int t = threadIdx.x, lane = t & 63, wid = t >> 6;
  const int nb = blockIdx.x, c = blockIdx.y;
  const int n0 = nb * 64;
  const int kbz = c * KCH;
  const int wr = wid >> 1, wc = wid & 1;
  const int l15 = lane & 15, l4 = lane >> 4;

  // A staging: 64 rows x 64 k f32 -> bf16; thread: row t>>3, 8-float seg t&7
  const int arow = t >> 3, kseg8 = t & 7;
  const float4* agz = (const float4*)(SK + (size_t)(n0 + arow) * 4096 + kbz + kseg8 * 8);
  const int awoff = arow * 128 + ((kseg8 ^ (arow & 7)) << 4);

  // B staging: 128 cols x 64 k bf16 = 16KB = 1024 granules, 2/thread
  int bcol[2], bgq[2], bldst[2];
#pragma unroll
  for (int j = 0; j < 2; ++j) {
    int G = j * 512 + t;
    bcol[j] = G >> 3;
    bgq[j] = (G & 7) ^ (bcol[j] & 7);
    bldst[j] = G * 16;
  }

  int aro, bro[4];
  {
    int row = wr * 16 + l15;
    aro = row * 128 + ((l4 ^ (row & 7)) << 4);
  }
#pragma unroll
  for (int n2 = 0; n2 < 4; ++n2) {
    int col = wc * 64 + n2 * 16 + l15;
    bro[n2] = col * 128 + ((l4 ^ (col & 7)) << 4);
  }

  f4 acc[4];
#pragma unroll
  for (int j = 0; j < 4; ++j) acc[j] = (f4){0.f, 0.f, 0.f, 0.f};

  // prologue: A(0) regs, B(0) async
  float4 va0 = agz[0], va1 = agz[1];
  FENCE();
  async16(Ytd + (size_t)bcol[0] * 4096 + kbz + bgq[0] * 8, sB0 + bldst[0]);
  async16(Ytd + (size_t)bcol[1] * 4096 + kbz + bgq[1] * 8, sB0 + bldst[1]);
  FENCE();
  char* sBc = sB0;
  char* sBn = sB1;
  for (int k = 0; k < 7; ++k) {
    SBAR(); FENCE();
    WAITV(2);  // A(k) regs ready (B(k) x2 fly)
    union { bh8 v; u16 u[8]; } p;
    p.u[0] = f2bf(va0.x); p.u[1] = f2bf(va0.y); p.u[2] = f2bf(va0.z); p.u[3] = f2bf(va0.w);
    p.u[4] = f2bf(va1.x); p.u[5] = f2bf(va1.y); p.u[6] = f2bf(va1.z); p.u[7] = f2bf(va1.w);
    *(bh8*)(sA + awoff) = p.v;
    FENCE();
    va0 = agz[(k + 1) * 16]; va1 = agz[(k + 1) * 16 + 1];  // issue A(k+1)
    FENCE();
    WAITVL(2);  // B(k) landed + sA write done (A(k+1) flying)
    SBAR(); FENCE();
    async16(Ytd + (size_t)bcol[0] * 4096 + kbz + bgq[0] * 8 + (k + 1) * 64, sBn + bldst[0]);
    async16(Ytd + (size_t)bcol[1] * 4096 + kbz + bgq[1] * 8 + (k + 1) * 64, sBn + bldst[1]);
    FENCE();
#pragma unroll
    for (int kk = 0; kk < 2; ++kk) {
      bh8 a = *(const bh8*)(sA + (aro ^ (kk << 6)));
#pragma unroll
      for (int n2 = 0; n2 < 4; ++n2) {
        bh8 bb = *(const bh8*)(sBc + (bro[n2] ^ (kk << 6)));
        acc[n2] = __builtin_amdgcn_mfma_f32_16x16x32_bf16(a, bb, acc[n2], 0, 0, 0);
      }
    }
    char* tp = sBc; sBc = sBn; sBn = tp;
  }
  // peeled last iter (k = 7)
  SBAR(); FENCE();
  WAITV(2);
  {
    union { bh8 v; u16 u[8]; } p;
    p.u[0] = f2bf(va0.x); p.u[1] = f2bf(va0.y); p.u[2] = f2bf(va0.z); p.u[3] = f2bf(va0.w);
    p.u[4] = f2bf(va1.x); p.u[5] = f2bf(va1.y); p.u[6] = f2bf(va1.z); p.u[7] = f2bf(va1.w);
    *(bh8*)(sA + awoff) = p.v;
  }
  WAITVL(0);
  SBAR(); FENCE();
#pragma unroll
  for (int kk = 0; kk < 2; ++kk) {
    bh8 a = *(const bh8*)(sA + (aro ^ (kk << 6)));
#pragma unroll
    for (int n2 = 0; n2 < 4; ++n2) {
      bh8 bb = *(const bh8*)(sBc + (bro[n2] ^ (kk << 6)));
      acc[n2] = __builtin_amdgcn_mfma_f32_16x16x32_bf16(a, bb, acc[n2], 0, 0, 0);
    }
  }

  float* Z = Zp + (size_t)c * (N_SZ * 128) + (size_t)n0 * 128;
#pragma unroll
  for (int n2 = 0; n2 < 4; ++n2)
#pragma unroll
    for (int q = 0; q < 4; ++q) {
      int r = wr * 16 + l4 * 4 + q;
      int cc = wc * 64 + n2 * 16 + l15;
      Z[r * 128 + cc] = acc[n2][q];
    }
}

// ---------------------------------------------------------------------------
// K2b: s_dst[n][i] = s_src[n][i] + tanh(sum_c Zp[c][n][i] + b[i])
// [R10 structure; explicit src/dst so depth 0 reads self_act]
// ---------------------------------------------------------------------------
__global__ void k2b_kernel(const float* __restrict__ s_src, float* __restrict__ s_dst,
                           const float* __restrict__ Zp, const float* __restrict__ bd) {
  int idx = blockIdx.x * 256 + threadIdx.x;
  float v = bd[idx & 127];
#pragma unroll
  for (int c = 0; c < SPLITK; ++c) v += Zp[(size_t)c * (N_SZ * 128) + idx];
  s_dst[idx] = s_src[idx] + fast_tanh(v);
}

// ---------------------------------------------------------------------------
// phaseB v6b: out = act + sum_d tanh(kern @ y_d + b_d).  [R10-exact, frozen]
// grid 256, block 1024 (16 waves = 4/SIMD intra-block TLP). Tile 128r x
// 512tc, K-step 32, 128 iters. wr = wid>>3, wc = wid&7; acc[4 mf][4 d].
// ---------------------------------------------------------------------------
__global__ __launch_bounds__(1024, 4) void pB_kernel(
    const float* __restrict__ A, const u16* __restrict__ Yt,
    const float* __restrict__ act, const float* __restrict__ bias,
    float* __restrict__ outA) {
  __shared__ char smem[8192 + 2 * 32768];
  char* sA = smem;
  char* sB0 = smem + 8192;
  char* sB1 = smem + 8192 + 32768;
  const int t = threadIdx.x, lane = t & 63, wid = t >> 6;
  const int wr = wid >> 3, wc = wid & 7;
  const int m0 = blockIdx.x * 128;
  const int l15 = lane & 15, l4 = lane >> 4;

  const int arow = t >> 3, aseg = t & 7;
  const float4* agp = (const float4*)(A + (size_t)(m0 + arow) * 4096 + aseg * 4);
  const int awoff = arow * 64 + (((aseg >> 1) ^ (arow & 3)) << 4) + ((aseg & 1) << 3);

  const u16* bsrc[2];
  int bldst[2];
#pragma unroll
  for (int j = 0; j < 2; ++j) {
    int G = j * 1024 + t;
    int col = G >> 2;
    int g = (G & 3) ^ (col & 3);
    bsrc[j] = Yt + (size_t)col * 4096 + g * 8;
    bldst[j] = (j * 16 + wid) * 1024;  // wave-uniform base (+ lane*16 by HW)
  }

  int aro[4], bro[4];
#pragma unroll
  for (int mf = 0; mf < 4; ++mf) {
    int row = wr * 64 + mf * 16 + l15;  // in [0,128) exactly once over (wr,mf)
    aro[mf] = row * 64 + ((l4 ^ (row & 3)) << 4);
  }
#pragma unroll
  for (int d = 0; d < 4; ++d) {
    int tc = d * 128 + wc * 16 + l15;   // in [0,512)
    bro[d] = tc * 64 + ((l4 ^ (tc & 3)) << 4);
  }

  f4 acc[4][4];  // [mf][d]
#pragma unroll
  for (int i = 0; i < 4; ++i)
#pragma unroll
    for (int j = 0; j < 4; ++j) acc[i][j] = (f4){0.f, 0.f, 0.f, 0.f};

  float4 va = agp[0];
  FENCE();
  async16(bsrc[0], sB0 + bldst[0]);
  async16(bsrc[1], sB0 + bldst[1]);
  FENCE();

  char* sBc = sB0;
  char* sBn = sB1;
#pragma unroll 1
  for (int k = 0; k < 127; ++k) {
    SBAR(); FENCE();
    WAITV(2);  // retire A(k); B(k) x2 may fly
    union { uint2 v; u16 u[4]; } p;
    p.u[0] = f2bf(va.x); p.u[1] = f2bf(va.y); p.u[2] = f2bf(va.z); p.u[3] = f2bf(va.w);
    *(uint2*)(sA + awoff) = p.v;
    FENCE();
    va = agp[(k + 1) * 8];  // issue A(k+1)
    FENCE();
    WAITVL(1);  // retire B(k) x2; A(k+1) stays in flight
    SBAR(); FENCE();
    async16(bsrc[0] + (k + 1) * 32, sBn + bldst[0]);
    async16(bsrc[1] + (k + 1) * 32, sBn + bldst[1]);
    FENCE();
    bh8 af[4];
#pragma unroll
    for (int mf = 0; mf < 4; ++mf) af[mf] = *(const bh8*)(sA + aro[mf]);
#pragma unroll
    for (int d = 0; d < 4; ++d) {
      bh8 b = *(const bh8*)(sBc + bro[d]);
#pragma unroll
      for (int mf = 0; mf < 4; ++mf)
        acc[mf][d] = __builtin_amdgcn_mfma_f32_16x16x32_bf16(af[mf], b, acc[mf][d], 0, 0, 0);
    }
    char* tp = sBc; sBc = sBn; sBn = tp;
  }
  SBAR(); FENCE();
  WAITV(2);
  {
    union { uint2 v; u16 u[4]; } p;
    p.u[0] = f2bf(va.x); p.u[1] = f2bf(va.y); p.u[2] = f2bf(va.z); p.u[3] = f2bf(va.w);
    *(uint2*)(sA + awoff) = p.v;
  }
  WAITVL(0);
  SBAR(); FENCE();
  {
    bh8 af[4];
#pragma unroll
    for (int mf = 0; mf < 4; ++mf) af[mf] = *(const bh8*)(sA + aro[mf]);
#pragma unroll
    for (int d = 0; d < 4; ++d) {
      bh8 b = *(const bh8*)(sBc + bro[d]);
#pragma unroll
      for (int mf = 0; mf < 4; ++mf)
        acc[mf][d] = __builtin_amdgcn_mfma_f32_16x16x32_bf16(af[mf], b, acc[mf][d], 0, 0, 0);
    }
  }

  float bsv[4];
#pragma unroll
  for (int d = 0; d < 4; ++d) bsv[d] = bias[d * 128 + wc * 16 + l15];
#pragma unroll
  for (int mf = 0; mf < 4; ++mf)
#pragma unroll
    for (int q = 0; q < 4; ++q) {
      int r = m0 + wr * 64 + mf * 16 + l4 * 4 + q;
      int c = wc * 16 + l15;
      float s = 0.f;
#pragma unroll
      for (int d = 0; d < 4; ++d) s += fast_tanh(acc[mf][d][q] + bsv[d]);
      size_t o = (size_t)r * 128 + c;
      outA[o] = act[o] + s;
    }
}

// ---------------------------------------------------------------------------
extern "C" void kernel_launch(void* const* d_in, const int* in_sizes, int n_in,
                              void* d_out, int out_size, void* d_ws, size_t ws_size,
                              hipStream_t stream) {
  const float* act = (const float*)d_in[0];
  const float* self_act = (const float*)d_in[1];
  const float* kern = (const float*)d_in[2];
  const float* self_kern = (const float*)d_in[3];
  const float* weights = (const float*)d_in[4];
  const float* bias = (const float*)d_in[5];
  float* out = (float*)d_out;
  float* s_buf = out + (size_t)M_SZ * 128;  // self_act state lives in its output slot

  char* ws = (char*)d_ws;
  u16* Yt = (u16*)ws;                          // [512][4096] bf16, 4 MB
  float* Zp = (float*)(ws + (4u << 20));       // [SPLITK][4096][128] f32, 16 MB

  for (int d = 0; d < DEPTHS; ++d) {
    const float* s_src = (d == 0) ? self_act : s_buf;
    k1_kernel<<<dim3(16, 16), 256, 0, stream>>>(s_src, weights + d * 16384,
                                                Yt + (size_t)d * 128 * 4096);
    k2a_kernel<<<dim3(64, SPLITK), 512, 0, stream>>>(self_kern,
                                                     Yt + (size_t)d * 128 * 4096, Zp);
    k2b_kernel<<<2048, 256, 0, stream>>>(s_src, s_buf, Zp, bias + d * 128);
  }
  pB_kernel<<<256, 1024, 0, stream>>>(kern, Yt, act, bias, out);
}

// Round 14
// 359.993 us; speedup vs baseline: 1.8363x; 1.0163x over previous
//
#include <hip/hip_runtime.h>

#define M_SZ 32768
#define N_SZ 4096
#define DEPTHS 4
#define SPLITK 8
#define KCH 512  // N_SZ / SPLITK

typedef __attribute__((ext_vector_type(8))) short bh8;   // 8 bf16 (4 VGPR) MFMA frag
typedef __attribute__((ext_vector_type(4))) float f4;    // MFMA accumulator
typedef unsigned short u16;
typedef unsigned int u32;

#define SBAR() __builtin_amdgcn_s_barrier()
#define FENCE() asm volatile("" ::: "memory")
#define WAITV(n) asm volatile("s_waitcnt vmcnt(" #n ")" ::: "memory")
#define WAITVL(n) asm volatile("s_waitcnt vmcnt(" #n ") lgkmcnt(0)" ::: "memory")

__device__ __forceinline__ u16 f2bf(float f) {
  u32 u = __float_as_uint(f);
  u = (u + 0x7FFFu + ((u >> 16) & 1u)) >> 16;  // RNE
  return (u16)u;
}

__device__ __forceinline__ float fast_tanh(float x) {
  float ax = __builtin_fabsf(x);
  float e = __builtin_exp2f(ax * 2.8853900817779268f);  // e^(2|x|)
  float r = 1.0f - 2.0f * __builtin_amdgcn_rcpf(e + 1.0f);
  return __builtin_copysignf(r, x);
}

__device__ __forceinline__ void async16(const void* g, void* l) {
  __builtin_amdgcn_global_load_lds((const __attribute__((address_space(1))) u32*)g,
                                   (__attribute__((address_space(3))) u32*)l, 16, 0, 0);
}

// ---------------------------------------------------------------------------
// K1: y_d[i][n] = sum_k s[n][k] * Wd[i][k]   (write TRANSPOSED [i][n], bf16)
// [R13-exact]
// ---------------------------------------------------------------------------
__global__ void k1_kernel(const float* __restrict__ s, const float* __restrict__ Wd,
                          u16* __restrict__ Ytd) {
  const int n = blockIdx.x * 256 + threadIdx.x;
  const int i0 = blockIdx.y * 8;
  float acc[8] = {0.f, 0.f, 0.f, 0.f, 0.f, 0.f, 0.f, 0.f};
  const float4* srow = (const float4*)(s + (size_t)n * 128);
#pragma unroll 4
  for (int k4 = 0; k4 < 32; ++k4) {
    float4 sv = srow[k4];
#pragma unroll
    for (int ii = 0; ii < 8; ++ii) {
      const float* w = Wd + (i0 + ii) * 128 + k4 * 4;
      acc[ii] = fmaf(sv.x, w[0], acc[ii]);
      acc[ii] = fmaf(sv.y, w[1], acc[ii]);
      acc[ii] = fmaf(sv.z, w[2], acc[ii]);
      acc[ii] = fmaf(sv.w, w[3], acc[ii]);
    }
  }
#pragma unroll
  for (int ii = 0; ii < 8; ++ii)
    Ytd[(size_t)(i0 + ii) * 4096 + n] = f2bf(acc[ii]);
}

// ---------------------------------------------------------------------------
// K2a64: split-K partials of self_kernel @ y_d.  [R13-exact]
// ---------------------------------------------------------------------------
__global__ __launch_bounds__(512, 4) void k2a_kernel(
    const float* __restrict__ SK, const u16* __restrict__ Ytd, float* __restrict__ Zp) {
  __shared__ char smem[8192 + 2 * 16384];
  char* sA = smem;
  char* sB0 = smem + 8192;
  char* sB1 = smem + 8192 + 16384;
  const int t = threadIdx.x, lane = t & 63, wid = t >> 6;
  const int nb = blockIdx.x, c = blockIdx.y;
  const int n0 = nb * 64;
  const int kbz = c * KCH;
  const int wr = wid >> 1, wc = wid & 1;
  const int l15 = lane & 15, l4 = lane >> 4;

  const int arow = t >> 3, kseg8 = t & 7;
  const float4* agz = (const float4*)(SK + (size_t)(n0 + arow) * 4096 + kbz + kseg8 * 8);
  const int awoff = arow * 128 + ((kseg8 ^ (arow & 7)) << 4);

  int bcol[2], bgq[2], bldst[2];
#pragma unroll
  for (int j = 0; j < 2; ++j) {
    int G = j * 512 + t;
    bcol[j] = G >> 3;
    bgq[j] = (G & 7) ^ (bcol[j] & 7);
    bldst[j] = G * 16;
  }

  int aro, bro[4];
  {
    int row = wr * 16 + l15;
    aro = row * 128 + ((l4 ^ (row & 7)) << 4);
  }
#pragma unroll
  for (int n2 = 0; n2 < 4; ++n2) {
    int col = wc * 64 + n2 * 16 + l15;
    bro[n2] = col * 128 + ((l4 ^ (col & 7)) << 4);
  }

  f4 acc[4];
#pragma unroll
  for (int j = 0; j < 4; ++j) acc[j] = (f4){0.f, 0.f, 0.f, 0.f};

  float4 va0 = agz[0], va1 = agz[1];
  FENCE();
  async16(Ytd + (size_t)bcol[0] * 4096 + kbz + bgq[0] * 8, sB0 + bldst[0]);
  async16(Ytd + (size_t)bcol[1] * 4096 + kbz + bgq[1] * 8, sB0 + bldst[1]);
  FENCE();
  char* sBc = sB0;
  char* sBn = sB1;
  for (int k = 0; k < 7; ++k) {
    SBAR(); FENCE();
    WAITV(2);
    union { bh8 v; u16 u[8]; } p;
    p.u[0] = f2bf(va0.x); p.u[1] = f2bf(va0.y); p.u[2] = f2bf(va0.z); p.u[3] = f2bf(va0.w);
    p.u[4] = f2bf(va1.x); p.u[5] = f2bf(va1.y); p.u[6] = f2bf(va1.z); p.u[7] = f2bf(va1.w);
    *(bh8*)(sA + awoff) = p.v;
    FENCE();
    va0 = agz[(k + 1) * 16]; va1 = agz[(k + 1) * 16 + 1];
    FENCE();
    WAITVL(2);
    SBAR(); FENCE();
    async16(Ytd + (size_t)bcol[0] * 4096 + kbz + bgq[0] * 8 + (k + 1) * 64, sBn + bldst[0]);
    async16(Ytd + (size_t)bcol[1] * 4096 + kbz + bgq[1] * 8 + (k + 1) * 64, sBn + bldst[1]);
    FENCE();
#pragma unroll
    for (int kk = 0; kk < 2; ++kk) {
      bh8 a = *(const bh8*)(sA + (aro ^ (kk << 6)));
#pragma unroll
      for (int n2 = 0; n2 < 4; ++n2) {
        bh8 bb = *(const bh8*)(sBc + (bro[n2] ^ (kk << 6)));
        acc[n2] = __builtin_amdgcn_mfma_f32_16x16x32_bf16(a, bb, acc[n2], 0, 0, 0);
      }
    }
    char* tp = sBc; sBc = sBn; sBn = tp;
  }
  SBAR(); FENCE();
  WAITV(2);
  {
    union { bh8 v; u16 u[8]; } p;
    p.u[0] = f2bf(va0.x); p.u[1] = f2bf(va0.y); p.u[2] = f2bf(va0.z); p.u[3] = f2bf(va0.w);
    p.u[4] = f2bf(va1.x); p.u[5] = f2bf(va1.y); p.u[6] = f2bf(va1.z); p.u[7] = f2bf(va1.w);
    *(bh8*)(sA + awoff) = p.v;
  }
  WAITVL(0);
  SBAR(); FENCE();
#pragma unroll
  for (int kk = 0; kk < 2; ++kk) {
    bh8 a = *(const bh8*)(sA + (aro ^ (kk << 6)));
#pragma unroll
    for (int n2 = 0; n2 < 4; ++n2) {
      bh8 bb = *(const bh8*)(sBc + (bro[n2] ^ (kk << 6)));
      acc[n2] = __builtin_amdgcn_mfma_f32_16x16x32_bf16(a, bb, acc[n2], 0, 0, 0);
    }
  }

  float* Z = Zp + (size_t)c * (N_SZ * 128) + (size_t)n0 * 128;
#pragma unroll
  for (int n2 = 0; n2 < 4; ++n2)
#pragma unroll
    for (int q = 0; q < 4; ++q) {
      int r = wr * 16 + l4 * 4 + q;
      int cc = wc * 64 + n2 * 16 + l15;
      Z[r * 128 + cc] = acc[n2][q];
    }
}

// ---------------------------------------------------------------------------
// K2b: s_dst[n][i] = s_src[n][i] + tanh(sum_c Zp[c][n][i] + b[i])  [R13-exact]
// ---------------------------------------------------------------------------
__global__ void k2b_kernel(const float* __restrict__ s_src, float* __restrict__ s_dst,
                           const float* __restrict__ Zp, const float* __restrict__ bd) {
  int idx = blockIdx.x * 256 + threadIdx.x;
  float v = bd[idx & 127];
#pragma unroll
  for (int c = 0; c < SPLITK; ++c) v += Zp[(size_t)c * (N_SZ * 128) + idx];
  s_dst[idx] = s_src[idx] + fast_tanh(v);
}

// ---------------------------------------------------------------------------
// phaseB v7: out = act + sum_d tanh(kern @ y_d + b_d). Single 512MB A pass.
// Same decomposition as v6b (grid 256, 1024 thr, 16 waves wr=wid>>3 wc=wid&7,
// acc[4 mf][4 d]) but K-step 64 -> 64 iters: HALVES barrier+waitcnt overhead
// at identical LDS-read totals. Staging/read algebra = k2a64's proven
// 128B-row XOR family (kseg8^(row&7); frag reads aro^(kk<<6)).
// LDS 144KB = sA 16K + sB 2x64K (1 block/CU). Queue [A x2, B x4]:
// top WAITV(4), mid WAITVL(2); never 0 until peel.
// ---------------------------------------------------------------------------
__global__ __launch_bounds__(1024, 4) void pB_kernel(
    const float* __restrict__ A, const u16* __restrict__ Yt,
    const float* __restrict__ act, const float* __restrict__ bias,
    float* __restrict__ outA) {
  __shared__ char smem[16384 + 2 * 65536];
  char* sA = smem;
  char* sB0 = smem + 16384;
  char* sB1 = smem + 16384 + 65536;
  const int t = threadIdx.x, lane = t & 63, wid = t >> 6;
  const int wr = wid >> 3, wc = wid & 7;
  const int m0 = blockIdx.x * 128;
  const int l15 = lane & 15, l4 = lane >> 4;

  // A staging: 128 rows x 64 k f32 (32KB src) -> 16KB bf16; 8 f32/thread.
  const int arow = t >> 3, kseg8 = t & 7;
  const float4* agp = (const float4*)(A + (size_t)(m0 + arow) * 4096 + kseg8 * 8);
  const int awoff = arow * 128 + ((kseg8 ^ (arow & 7)) << 4);

  // B staging: 512 tc x 64 k bf16 = 64KB; 4 async16/thread (pre-swizzled src).
  const u16* bsrc[4];
  int bldst[4];
#pragma unroll
  for (int j = 0; j < 4; ++j) {
    int G = j * 1024 + t;
    int col = G >> 3;
    int gq = (G & 7) ^ (col & 7);
    bsrc[j] = Yt + (size_t)col * 4096 + gq * 8;
    bldst[j] = G * 16;  // wave-uniform base + lane*16
  }

  int aro[4], bro[4];
#pragma unroll
  for (int mf = 0; mf < 4; ++mf) {
    int row = wr * 64 + mf * 16 + l15;  // [0,128) exactly once over (wr,mf)
    aro[mf] = row * 128 + ((l4 ^ (row & 7)) << 4);
  }
#pragma unroll
  for (int d = 0; d < 4; ++d) {
    int tc = d * 128 + wc * 16 + l15;   // [0,512)
    bro[d] = tc * 128 + ((l4 ^ (tc & 7)) << 4);
  }

  f4 acc[4][4];  // [mf][d]
#pragma unroll
  for (int i = 0; i < 4; ++i)
#pragma unroll
    for (int j = 0; j < 4; ++j) acc[i][j] = (f4){0.f, 0.f, 0.f, 0.f};

  // prologue: A(0) x2, then B(0) x4 (FIFO [A,A,B,B,B,B])
  float4 va0 = agp[0], va1 = agp[1];
  FENCE();
#pragma unroll
  for (int j = 0; j < 4; ++j) async16(bsrc[j], sB0 + bldst[j]);
  FENCE();

  char* sBc = sB0;
  char* sBn = sB1;
#pragma unroll 1
  for (int k = 0; k < 63; ++k) {
    SBAR(); FENCE();
    WAITV(4);  // drain A(k) x2; B(k) x4 in flight
    union { bh8 v; u16 u[8]; } p;
    p.u[0] = f2bf(va0.x); p.u[1] = f2bf(va0.y); p.u[2] = f2bf(va0.z); p.u[3] = f2bf(va0.w);
    p.u[4] = f2bf(va1.x); p.u[5] = f2bf(va1.y); p.u[6] = f2bf(va1.z); p.u[7] = f2bf(va1.w);
    *(bh8*)(sA + awoff) = p.v;
    FENCE();
    va0 = agp[(k + 1) * 16]; va1 = agp[(k + 1) * 16 + 1];  // issue A(k+1)
    FENCE();
    WAITVL(2);  // drain B(k) x4 + sA write visible; A(k+1) x2 in flight
    SBAR(); FENCE();
#pragma unroll
    for (int j = 0; j < 4; ++j) async16(bsrc[j] + (k + 1) * 64, sBn + bldst[j]);
    FENCE();
#pragma unroll
    for (int kk = 0; kk < 2; ++kk) {
      bh8 af[4];
#pragma unroll
      for (int mf = 0; mf < 4; ++mf) af[mf] = *(const bh8*)(sA + (aro[mf] ^ (kk << 6)));
#pragma unroll
      for (int d = 0; d < 4; ++d) {
        bh8 b = *(const bh8*)(sBc + (bro[d] ^ (kk << 6)));
#pragma unroll
        for (int mf = 0; mf < 4; ++mf)
          acc[mf][d] = __builtin_amdgcn_mfma_f32_16x16x32_bf16(af[mf], b, acc[mf][d], 0, 0, 0);
      }
    }
    char* tp = sBc; sBc = sBn; sBn = tp;
  }
  // peeled last iter (k = 63)
  SBAR(); FENCE();
  WAITV(4);
  {
    union { bh8 v; u16 u[8]; } p;
    p.u[0] = f2bf(va0.x); p.u[1] = f2bf(va0.y); p.u[2] = f2bf(va0.z); p.u[3] = f2bf(va0.w);
    p.u[4] = f2bf(va1.x); p.u[5] = f2bf(va1.y); p.u[6] = f2bf(va1.z); p.u[7] = f2bf(va1.w);
    *(bh8*)(sA + awoff) = p.v;
  }
  WAITVL(0);
  SBAR(); FENCE();
#pragma unroll
  for (int kk = 0; kk < 2; ++kk) {
    bh8 af[4];
#pragma unroll
    for (int mf = 0; mf < 4; ++mf) af[mf] = *(const bh8*)(sA + (aro[mf] ^ (kk << 6)));
#pragma unroll
    for (int d = 0; d < 4; ++d) {
      bh8 b = *(const bh8*)(sBc + (bro[d] ^ (kk << 6)));
#pragma unroll
      for (int mf = 0; mf < 4; ++mf)
        acc[mf][d] = __builtin_amdgcn_mfma_f32_16x16x32_bf16(af[mf], b, acc[mf][d], 0, 0, 0);
    }
  }

  float bsv[4];
#pragma unroll
  for (int d = 0; d < 4; ++d) bsv[d] = bias[d * 128 + wc * 16 + l15];
#pragma unroll
  for (int mf = 0; mf < 4; ++mf)
#pragma unroll
    for (int q = 0; q < 4; ++q) {
      int r = m0 + wr * 64 + mf * 16 + l4 * 4 + q;
      int c = wc * 16 + l15;
      float s = 0.f;
#pragma unroll
      for (int d = 0; d < 4; ++d) s += fast_tanh(acc[mf][d][q] + bsv[d]);
      size_t o = (size_t)r * 128 + c;
      outA[o] = act[o] + s;
    }
}

// ---------------------------------------------------------------------------
extern "C" void kernel_launch(void* const* d_in, const int* in_sizes, int n_in,
                              void* d_out, int out_size, void* d_ws, size_t ws_size,
                              hipStream_t stream) {
  const float* act = (const float*)d_in[0];
  const float* self_act = (const float*)d_in[1];
  const float* kern = (const float*)d_in[2];
  const float* self_kern = (const float*)d_in[3];
  const float* weights = (const float*)d_in[4];
  const float* bias = (const float*)d_in[5];
  float* out = (float*)d_out;
  float* s_buf = out + (size_t)M_SZ * 128;  // self_act state lives in its output slot

  char* ws = (char*)d_ws;
  u16* Yt = (u16*)ws;                          // [512][4096] bf16, 4 MB
  float* Zp = (float*)(ws + (4u << 20));       // [SPLITK][4096][128] f32, 16 MB

  for (int d = 0; d < DEPTHS; ++d) {
    const float* s_src = (d == 0) ? self_act : s_buf;
    k1_kernel<<<dim3(16, 16), 256, 0, stream>>>(s_src, weights + d * 16384,
                                                Yt + (size_t)d * 128 * 4096);
    k2a_kernel<<<dim3(64, SPLITK), 512, 0, stream>>>(self_kern,
                                                     Yt + (size_t)d * 128 * 4096, Zp);
    k2b_kernel<<<2048, 256, 0, stream>>>(s_src, s_buf, Zp, bias + d * 128);
  }
  pB_kernel<<<256, 1024, 0, stream>>>(kern, Yt, act, bias, out);
}

// Round 15
// 333.874 us; speedup vs baseline: 1.9800x; 1.0782x over previous
//
#include <hip/hip_runtime.h>

#define M_SZ 32768
#define N_SZ 4096
#define DEPTHS 4
#define SPLITK 8
#define KCH 512  // N_SZ / SPLITK

typedef __attribute__((ext_vector_type(8))) short bh8;   // 8 bf16 (4 VGPR) MFMA frag
typedef __attribute__((ext_vector_type(4))) float f4;    // MFMA accumulator
typedef unsigned short u16;
typedef unsigned int u32;

#define SBAR() __builtin_amdgcn_s_barrier()
#define FENCE() asm volatile("" ::: "memory")
#define WAITV(n) asm volatile("s_waitcnt vmcnt(" #n ")" ::: "memory")
#define WAITVL(n) asm volatile("s_waitcnt vmcnt(" #n ") lgkmcnt(0)" ::: "memory")

__device__ __forceinline__ u16 f2bf(float f) {
  u32 u = __float_as_uint(f);
  u = (u + 0x7FFFu + ((u >> 16) & 1u)) >> 16;  // RNE
  return (u16)u;
}

__device__ __forceinline__ float fast_tanh(float x) {
  float ax = __builtin_fabsf(x);
  float e = __builtin_exp2f(ax * 2.8853900817779268f);  // e^(2|x|)
  float r = 1.0f - 2.0f * __builtin_amdgcn_rcpf(e + 1.0f);
  return __builtin_copysignf(r, x);
}

__device__ __forceinline__ void async16(const void* g, void* l) {
  __builtin_amdgcn_global_load_lds((const __attribute__((address_space(1))) u32*)g,
                                   (__attribute__((address_space(3))) u32*)l, 16, 0, 0);
}

// ---------------------------------------------------------------------------
// K1: y_d[i][n] = sum_k s[n][k] * Wd[i][k]   (write TRANSPOSED [i][n], bf16)
// [R14-exact; used for depth 0 only]
// ---------------------------------------------------------------------------
__global__ void k1_kernel(const float* __restrict__ s, const float* __restrict__ Wd,
                          u16* __restrict__ Ytd) {
  const int n = blockIdx.x * 256 + threadIdx.x;
  const int i0 = blockIdx.y * 8;
  float acc[8] = {0.f, 0.f, 0.f, 0.f, 0.f, 0.f, 0.f, 0.f};
  const float4* srow = (const float4*)(s + (size_t)n * 128);
#pragma unroll 4
  for (int k4 = 0; k4 < 32; ++k4) {
    float4 sv = srow[k4];
#pragma unroll
    for (int ii = 0; ii < 8; ++ii) {
      const float* w = Wd + (i0 + ii) * 128 + k4 * 4;
      acc[ii] = fmaf(sv.x, w[0], acc[ii]);
      acc[ii] = fmaf(sv.y, w[1], acc[ii]);
      acc[ii] = fmaf(sv.z, w[2], acc[ii]);
      acc[ii] = fmaf(sv.w, w[3], acc[ii]);
    }
  }
#pragma unroll
  for (int ii = 0; ii < 8; ++ii)
    Ytd[(size_t)(i0 + ii) * 4096 + n] = f2bf(acc[ii]);
}

// ---------------------------------------------------------------------------
// K2a64: split-K partials of self_kernel @ y_d.  [R14-exact]
// ---------------------------------------------------------------------------
__global__ __launch_bounds__(512, 4) void k2a_kernel(
    const float* __restrict__ SK, const u16* __restrict__ Ytd, float* __restrict__ Zp) {
  __shared__ char smem[8192 + 2 * 16384];
  char* sA = smem;
  char* sB0 = smem + 8192;
  char* sB1 = smem + 8192 + 16384;
  const int t = threadIdx.x, lane = t & 63, wid = t >> 6;
  const int nb = blockIdx.x, c = blockIdx.y;
  const int n0 = nb * 64;
  const int kbz = c * KCH;
  const int wr = wid >> 1, wc = wid & 1;
  const int l15 = lane & 15, l4 = lane >> 4;

  const int arow = t >> 3, kseg8 = t & 7;
  const float4* agz = (const float4*)(SK + (size_t)(n0 + arow) * 4096 + kbz + kseg8 * 8);
  const int awoff = arow * 128 + ((kseg8 ^ (arow & 7)) << 4);

  int bcol[2], bgq[2], bldst[2];
#pragma unroll
  for (int j = 0; j < 2; ++j) {
    int G = j * 512 + t;
    bcol[j] = G >> 3;
    bgq[j] = (G & 7) ^ (bcol[j] & 7);
    bldst[j] = G * 16;
  }

  int aro, bro[4];
  {
    int row = wr * 16 + l15;
    aro = row * 128 + ((l4 ^ (row & 7)) << 4);
  }
#pragma unroll
  for (int n2 = 0; n2 < 4; ++n2) {
    int col = wc * 64 + n2 * 16 + l15;
    bro[n2] = col * 128 + ((l4 ^ (col & 7)) << 4);
  }

  f4 acc[4];
#pragma unroll
  for (int j = 0; j < 4; ++j) acc[j] = (f4){0.f, 0.f, 0.f, 0.f};

  float4 va0 = agz[0], va1 = agz[1];
  FENCE();
  async16(Ytd + (size_t)bcol[0] * 4096 + kbz + bgq[0] * 8, sB0 + bldst[0]);
  async16(Ytd + (size_t)bcol[1] * 4096 + kbz + bgq[1] * 8, sB0 + bldst[1]);
  FENCE();
  char* sBc = sB0;
  char* sBn = sB1;
  for (int k = 0; k < 7; ++k) {
    SBAR(); FENCE();
    WAITV(2);
    union { bh8 v; u16 u[8]; } p;
    p.u[0] = f2bf(va0.x); p.u[1] = f2bf(va0.y); p.u[2] = f2bf(va0.z); p.u[3] = f2bf(va0.w);
    p.u[4] = f2bf(va1.x); p.u[5] = f2bf(va1.y); p.u[6] = f2bf(va1.z); p.u[7] = f2bf(va1.w);
    *(bh8*)(sA + awoff) = p.v;
    FENCE();
    va0 = agz[(k + 1) * 16]; va1 = agz[(k + 1) * 16 + 1];
    FENCE();
    WAITVL(2);
    SBAR(); FENCE();
    async16(Ytd + (size_t)bcol[0] * 4096 + kbz + bgq[0] * 8 + (k + 1) * 64, sBn + bldst[0]);
    async16(Ytd + (size_t)bcol[1] * 4096 + kbz + bgq[1] * 8 + (k + 1) * 64, sBn + bldst[1]);
    FENCE();
#pragma unroll
    for (int kk = 0; kk < 2; ++kk) {
      bh8 a = *(const bh8*)(sA + (aro ^ (kk << 6)));
#pragma unroll
      for (int n2 = 0; n2 < 4; ++n2) {
        bh8 bb = *(const bh8*)(sBc + (bro[n2] ^ (kk << 6)));
        acc[n2] = __builtin_amdgcn_mfma_f32_16x16x32_bf16(a, bb, acc[n2], 0, 0, 0);
      }
    }
    char* tp = sBc; sBc = sBn; sBn = tp;
  }
  SBAR(); FENCE();
  WAITV(2);
  {
    union { bh8 v; u16 u[8]; } p;
    p.u[0] = f2bf(va0.x); p.u[1] = f2bf(va0.y); p.u[2] = f2bf(va0.z); p.u[3] = f2bf(va0.w);
    p.u[4] = f2bf(va1.x); p.u[5] = f2bf(va1.y); p.u[6] = f2bf(va1.z); p.u[7] = f2bf(va1.w);
    *(bh8*)(sA + awoff) = p.v;
  }
  WAITVL(0);
  SBAR(); FENCE();
#pragma unroll
  for (int kk = 0; kk < 2; ++kk) {
    bh8 a = *(const bh8*)(sA + (aro ^ (kk << 6)));
#pragma unroll
    for (int n2 = 0; n2 < 4; ++n2) {
      bh8 bb = *(const bh8*)(sBc + (bro[n2] ^ (kk << 6)));
      acc[n2] = __builtin_amdgcn_mfma_f32_16x16x32_bf16(a, bb, acc[n2], 0, 0, 0);
    }
  }

  float* Z = Zp + (size_t)c * (N_SZ * 128) + (size_t)n0 * 128;
#pragma unroll
  for (int n2 = 0; n2 < 4; ++n2)
#pragma unroll
    for (int q = 0; q < 4; ++q) {
      int r = wr * 16 + l4 * 4 + q;
      int cc = wc * 64 + n2 * 16 + l15;
      Z[r * 128 + cc] = acc[n2][q];
    }
}

// ---------------------------------------------------------------------------
// K2b: s_dst[n][i] = s_src[n][i] + tanh(sum_c Zp[c][n][i] + b[i])
// [R14-exact; used for final depth only]
// ---------------------------------------------------------------------------
__global__ void k2b_kernel(const float* __restrict__ s_src, float* __restrict__ s_dst,
                           const float* __restrict__ Zp, const float* __restrict__ bd) {
  int idx = blockIdx.x * 256 + threadIdx.x;
  float v = bd[idx & 127];
#pragma unroll
  for (int c = 0; c < SPLITK; ++c) v += Zp[(size_t)c * (N_SZ * 128) + idx];
  s_dst[idx] = s_src[idx] + fast_tanh(v);
}

// ---------------------------------------------------------------------------
// KB1: fused k2b(depth d) + k1(depth d+1).  y is row-local in n, so a block
// that computed s rows [n0,n0+16) can produce Yt[d+1][:, n0..n0+16) at once.
// grid 256 x 256 thr.  LDS: sS [16][132] f32 (8.4KB) + wlds [128][131] f32
// (67KB) = 75.5KB.  Phase1 = exact k2b math; Phase3 fma order = exact k1
// order (bit-identical outputs).
// Bank algebra: wlds pad 131 (odd) -> w-read bank (3i+k)%32, 2 lanes/bank
// (free, m136); sS reads are same-addr broadcast (free); wlds stores
// consecutive-c (free).
// ---------------------------------------------------------------------------
__global__ __launch_bounds__(256, 2) void kb1_kernel(
    const float* __restrict__ s_src, float* __restrict__ s_dst,
    const float* __restrict__ Zp, const float* __restrict__ bd,
    const float* __restrict__ Wnext, u16* __restrict__ Ytnext) {
  __shared__ float sS[16 * 132];
  __shared__ float wlds[128 * 131];
  const int t = threadIdx.x;
  const int n0 = blockIdx.x * 16;

  // Phase 2a: issue W loads (coalesced), interleaved by compiler with phase 1
#pragma unroll 8
  for (int j = 0; j < 64; ++j) {
    int li = j * 256 + t;
    int wr_ = li >> 7, wc_ = li & 127;
    wlds[wr_ * 131 + wc_] = Wnext[wr_ * 128 + wc_];
  }

  // Phase 1: k2b for rows [n0, n0+16)
#pragma unroll
  for (int e = 0; e < 8; ++e) {
    int idx = e * 256 + t;              // 0..2047
    int r = idx >> 7, c = idx & 127;
    size_t gi = (size_t)(n0 + r) * 128 + c;
    float v = bd[c];
#pragma unroll
    for (int cc = 0; cc < SPLITK; ++cc) v += Zp[(size_t)cc * (N_SZ * 128) + gi];
    float res = s_src[gi] + fast_tanh(v);
    s_dst[gi] = res;
    sS[r * 132 + c] = res;
  }
  __syncthreads();

  // Phase 3: y[i][n] for i = t&127, n = n0 + (t>>7)*8 .. +8
  const int i = t & 127, nh = t >> 7;
  float acc[8] = {0.f, 0.f, 0.f, 0.f, 0.f, 0.f, 0.f, 0.f};
  const float* wrow = wlds + i * 131;
#pragma unroll 4
  for (int k4 = 0; k4 < 32; ++k4) {
    float w0 = wrow[k4 * 4 + 0], w1 = wrow[k4 * 4 + 1];
    float w2 = wrow[k4 * 4 + 2], w3 = wrow[k4 * 4 + 3];
#pragma unroll
    for (int r = 0; r < 8; ++r) {
      float4 sv = *(const float4*)(sS + (nh * 8 + r) * 132 + k4 * 4);
      acc[r] = fmaf(sv.x, w0, acc[r]);
      acc[r] = fmaf(sv.y, w1, acc[r]);
      acc[r] = fmaf(sv.z, w2, acc[r]);
      acc[r] = fmaf(sv.w, w3, acc[r]);
    }
  }
  union { bh8 v; u16 u[8]; } o;
#pragma unroll
  for (int r = 0; r < 8; ++r) o.u[r] = f2bf(acc[r]);
  *(bh8*)(Ytnext + (size_t)i * 4096 + n0 + nh * 8) = o.v;
}

// ---------------------------------------------------------------------------
// phaseB v7: out = act + sum_d tanh(kern @ y_d + b_d).  [R14-exact, frozen]
// ---------------------------------------------------------------------------
__global__ __launch_bounds__(1024, 4) void pB_kernel(
    const float* __restrict__ A, const u16* __restrict__ Yt,
    const float* __restrict__ act, const float* __restrict__ bias,
    float* __restrict__ outA) {
  __shared__ char smem[16384 + 2 * 65536];
  char* sA = smem;
  char* sB0 = smem + 16384;
  char* sB1 = smem + 16384 + 65536;
  const int t = threadIdx.x, lane = t & 63, wid = t >> 6;
  const int wr = wid >> 3, wc = wid & 7;
  const int m0 = blockIdx.x * 128;
  const int l15 = lane & 15, l4 = lane >> 4;

  const int arow = t >> 3, kseg8 = t & 7;
  const float4* agp = (const float4*)(A + (size_t)(m0 + arow) * 4096 + kseg8 * 8);
  const int awoff = arow * 128 + ((kseg8 ^ (arow & 7)) << 4);

  const u16* bsrc[4];
  int bldst[4];
#pragma unroll
  for (int j = 0; j < 4; ++j) {
    int G = j * 1024 + t;
    int col = G >> 3;
    int gq = (G & 7) ^ (col & 7);
    bsrc[j] = Yt + (size_t)col * 4096 + gq * 8;
    bldst[j] = G * 16;  // wave-uniform base + lane*16
  }

  int aro[4], bro[4];
#pragma unroll
  for (int mf = 0; mf < 4; ++mf) {
    int row = wr * 64 + mf * 16 + l15;  // [0,128) exactly once over (wr,mf)
    aro[mf] = row * 128 + ((l4 ^ (row & 7)) << 4);
  }
#pragma unroll
  for (int d = 0; d < 4; ++d) {
    int tc = d * 128 + wc * 16 + l15;   // [0,512)
    bro[d] = tc * 128 + ((l4 ^ (tc & 7)) << 4);
  }

  f4 acc[4][4];  // [mf][d]
#pragma unroll
  for (int i = 0; i < 4; ++i)
#pragma unroll
    for (int j = 0; j < 4; ++j) acc[i][j] = (f4){0.f, 0.f, 0.f, 0.f};

  float4 va0 = agp[0], va1 = agp[1];
  FENCE();
#pragma unroll
  for (int j = 0; j < 4; ++j) async16(bsrc[j], sB0 + bldst[j]);
  FENCE();

  char* sBc = sB0;
  char* sBn = sB1;
#pragma unroll 1
  for (int k = 0; k < 63; ++k) {
    SBAR(); FENCE();
    WAITV(4);  // drain A(k) x2; B(k) x4 in flight
    union { bh8 v; u16 u[8]; } p;
    p.u[0] = f2bf(va0.x); p.u[1] = f2bf(va0.y); p.u[2] = f2bf(va0.z); p.u[3] = f2bf(va0.w);
    p.u[4] = f2bf(va1.x); p.u[5] = f2bf(va1.y); p.u[6] = f2bf(va1.z); p.u[7] = f2bf(va1.w);
    *(bh8*)(sA + awoff) = p.v;
    FENCE();
    va0 = agp[(k + 1) * 16]; va1 = agp[(k + 1) * 16 + 1];  // issue A(k+1)
    FENCE();
    WAITVL(2);  // drain B(k) x4 + sA write visible; A(k+1) x2 in flight
    SBAR(); FENCE();
#pragma unroll
    for (int j = 0; j < 4; ++j) async16(bsrc[j] + (k + 1) * 64, sBn + bldst[j]);
    FENCE();
#pragma unroll
    for (int kk = 0; kk < 2; ++kk) {
      bh8 af[4];
#pragma unroll
      for (int mf = 0; mf < 4; ++mf) af[mf] = *(const bh8*)(sA + (aro[mf] ^ (kk << 6)));
#pragma unroll
      for (int d = 0; d < 4; ++d) {
        bh8 b = *(const bh8*)(sBc + (bro[d] ^ (kk << 6)));
#pragma unroll
        for (int mf = 0; mf < 4; ++mf)
          acc[mf][d] = __builtin_amdgcn_mfma_f32_16x16x32_bf16(af[mf], b, acc[mf][d], 0, 0, 0);
      }
    }
    char* tp = sBc; sBc = sBn; sBn = tp;
  }
  SBAR(); FENCE();
  WAITV(4);
  {
    union { bh8 v; u16 u[8]; } p;
    p.u[0] = f2bf(va0.x); p.u[1] = f2bf(va0.y); p.u[2] = f2bf(va0.z); p.u[3] = f2bf(va0.w);
    p.u[4] = f2bf(va1.x); p.u[5] = f2bf(va1.y); p.u[6] = f2bf(va1.z); p.u[7] = f2bf(va1.w);
    *(bh8*)(sA + awoff) = p.v;
  }
  WAITVL(0);
  SBAR(); FENCE();
#pragma unroll
  for (int kk = 0; kk < 2; ++kk) {
    bh8 af[4];
#pragma unroll
    for (int mf = 0; mf < 4; ++mf) af[mf] = *(const bh8*)(sA + (aro[mf] ^ (kk << 6)));
#pragma unroll
    for (int d = 0; d < 4; ++d) {
      bh8 b = *(const bh8*)(sBc + (bro[d] ^ (kk << 6)));
#pragma unroll
      for (int mf = 0; mf < 4; ++mf)
        acc[mf][d] = __builtin_amdgcn_mfma_f32_16x16x32_bf16(af[mf], b, acc[mf][d], 0, 0, 0);
    }
  }

  float bsv[4];
#pragma unroll
  for (int d = 0; d < 4; ++d) bsv[d] = bias[d * 128 + wc * 16 + l15];
#pragma unroll
  for (int mf = 0; mf < 4; ++mf)
#pragma unroll
    for (int q = 0; q < 4; ++q) {
      int r = m0 + wr * 64 + mf * 16 + l4 * 4 + q;
      int c = wc * 16 + l15;
      float s = 0.f;
#pragma unroll
      for (int d = 0; d < 4; ++d) s += fast_tanh(acc[mf][d][q] + bsv[d]);
      size_t o = (size_t)r * 128 + c;
      outA[o] = act[o] + s;
    }
}

// ---------------------------------------------------------------------------
extern "C" void kernel_launch(void* const* d_in, const int* in_sizes, int n_in,
                              void* d_out, int out_size, void* d_ws, size_t ws_size,
                              hipStream_t stream) {
  const float* act = (const float*)d_in[0];
  const float* self_act = (const float*)d_in[1];
  const float* kern = (const float*)d_in[2];
  const float* self_kern = (const float*)d_in[3];
  const float* weights = (const float*)d_in[4];
  const float* bias = (const float*)d_in[5];
  float* out = (float*)d_out;
  float* s_buf = out + (size_t)M_SZ * 128;  // self_act state lives in its output slot

  char* ws = (char*)d_ws;
  u16* Yt = (u16*)ws;                          // [512][4096] bf16, 4 MB
  float* Zp = (float*)(ws + (4u << 20));       // [SPLITK][4096][128] f32, 16 MB

  // depth 0: y from self_act
  k1_kernel<<<dim3(16, 16), 256, 0, stream>>>(self_act, weights,
                                              Yt);
  for (int d = 0; d < DEPTHS; ++d) {
    const float* s_src = (d == 0) ? self_act : s_buf;
    k2a_kernel<<<dim3(64, SPLITK), 512, 0, stream>>>(self_kern,
                                                     Yt + (size_t)d * 128 * 4096, Zp);
    if (d < DEPTHS - 1) {
      // fused: s update (depth d) + y for depth d+1
      kb1_kernel<<<256, 256, 0, stream>>>(s_src, s_buf, Zp, bias + d * 128,
                                          weights + (d + 1) * 16384,
                                          Yt + (size_t)(d + 1) * 128 * 4096);
    } else {
      k2b_kernel<<<2048, 256, 0, stream>>>(s_src, s_buf, Zp, bias + d * 128);
    }
  }
  pB_kernel<<<256, 1024, 0, stream>>>(kern, Yt, act, bias, out);
}

// Round 17
// 312.936 us; speedup vs baseline: 2.1124x; 1.0669x over previous
//
#include <hip/hip_runtime.h>

#define M_SZ 32768
#define N_SZ 4096
#define DEPTHS 4
#define SPLITK 8
#define KCH 512  // N_SZ / SPLITK

typedef __attribute__((ext_vector_type(8))) short bh8;   // 8 bf16 (4 VGPR) MFMA frag
typedef __attribute__((ext_vector_type(4))) float f4;    // MFMA accumulator
typedef unsigned short u16;
typedef unsigned int u32;

#define SBAR() __builtin_amdgcn_s_barrier()
#define FENCE() asm volatile("" ::: "memory")
#define WAITV(n) asm volatile("s_waitcnt vmcnt(" #n ")" ::: "memory")
#define WAITVL(n) asm volatile("s_waitcnt vmcnt(" #n ") lgkmcnt(0)" ::: "memory")

__device__ __forceinline__ u16 f2bf(float f) {
  u32 u = __float_as_uint(f);
  u = (u + 0x7FFFu + ((u >> 16) & 1u)) >> 16;  // RNE
  return (u16)u;
}

__device__ __forceinline__ float fast_tanh(float x) {
  float ax = __builtin_fabsf(x);
  float e = __builtin_exp2f(ax * 2.8853900817779268f);  // e^(2|x|)
  float r = 1.0f - 2.0f * __builtin_amdgcn_rcpf(e + 1.0f);
  return __builtin_copysignf(r, x);
}

__device__ __forceinline__ void async16(const void* g, void* l) {
  __builtin_amdgcn_global_load_lds((const __attribute__((address_space(1))) u32*)g,
                                   (__attribute__((address_space(3))) u32*)l, 16, 0, 0);
}

// ---------------------------------------------------------------------------
// K1c: y_0[i][n] = sum_k s[n][k] * W0[i][k]  (transposed bf16)  [R15 math]
// + fused one-time SK f32 -> bf16 conversion. Same RNE f2bf -> identical
// downstream numerics.
// ---------------------------------------------------------------------------
__global__ void k1_kernel(const float* __restrict__ s, const float* __restrict__ Wd,
                          u16* __restrict__ Ytd, const float* __restrict__ SK,
                          u16* __restrict__ SKb) {
  const int t = threadIdx.x;
  const int n = blockIdx.x * 256 + t;
  const int i0 = blockIdx.y * 8;
  float acc[8] = {0.f, 0.f, 0.f, 0.f, 0.f, 0.f, 0.f, 0.f};
  const float4* srow = (const float4*)(s + (size_t)n * 128);
#pragma unroll 4
  for (int k4 = 0; k4 < 32; ++k4) {
    float4 sv = srow[k4];
#pragma unroll
    for (int ii = 0; ii < 8; ++ii) {
      const float* w = Wd + (i0 + ii) * 128 + k4 * 4;
      acc[ii] = fmaf(sv.x, w[0], acc[ii]);
      acc[ii] = fmaf(sv.y, w[1], acc[ii]);
      acc[ii] = fmaf(sv.z, w[2], acc[ii]);
      acc[ii] = fmaf(sv.w, w[3], acc[ii]);
    }
  }
#pragma unroll
  for (int ii = 0; ii < 8; ++ii)
    Ytd[(size_t)(i0 + ii) * 4096 + n] = f2bf(acc[ii]);

  // fused SK -> SKb conversion: block slice = 65536 floats
  const size_t cbase = ((size_t)blockIdx.y * 16 + blockIdx.x) * 65536;
#pragma unroll 4
  for (int cc = 0; cc < 32; ++cc) {
    size_t off = cbase + (size_t)cc * 2048 + (size_t)t * 8;
    float4 u0 = *(const float4*)(SK + off);
    float4 u1 = *(const float4*)(SK + off + 4);
    union { bh8 v; u16 u[8]; } pk;
    pk.u[0] = f2bf(u0.x); pk.u[1] = f2bf(u0.y); pk.u[2] = f2bf(u0.z); pk.u[3] = f2bf(u0.w);
    pk.u[4] = f2bf(u1.x); pk.u[5] = f2bf(u1.y); pk.u[6] = f2bf(u1.z); pk.u[7] = f2bf(u1.w);
    *(bh8*)(SKb + off) = pk.v;
  }
}

// ---------------------------------------------------------------------------
// K2a v4: split-K partials of SKb(bf16) @ y_d. Tile 64n x 128i, K-step 64,
// grid (64,8) = 512 blocks = 2 blocks/CU. BOTH operands staged via async16
// (A 1/thread 8KB, B 2/thread 16KB), double-buffered; no f32 A round-trip.
// Rhythm: prologue L(0),L(1); per iter WAITV(3) [retire k's 3, k+1's fly],
// SBAR, compute, SBAR, issue L(k+2); peeled tail WAITV(0).
// LDS buffer addresses computed arithmetically (no LDS-pointer array --
// that was R16's illegal static addrspacecast initializer).
// LDS 48KB = sA 2x8K + sB 2x16K.
// ---------------------------------------------------------------------------
__global__ __launch_bounds__(512, 4) void k2a_kernel(
    const u16* __restrict__ SKb, const u16* __restrict__ Ytd, float* __restrict__ Zp) {
  __shared__ char smem[2 * 8192 + 2 * 16384];
#define SA_BUF(BUF) (smem + (BUF) * 8192)
#define SB_BUF(BUF) (smem + 16384 + (BUF) * 16384)
  const int t = threadIdx.x, lane = t & 63, wid = t >> 6;
  const int nb = blockIdx.x, c = blockIdx.y;
  const int n0 = nb * 64;
  const int kbz = c * KCH;
  const int wr = wid >> 1, wc = wid & 1;
  const int l15 = lane & 15, l4 = lane >> 4;

  // A staging: granule G = t -> row G>>3, seg G&7; src granule gq = seg^(row&7)
  const int arow_g = t >> 3, aseg = t & 7;
  const int agq = aseg ^ (arow_g & 7);
  const u16* asrc = SKb + (size_t)(n0 + arow_g) * 4096 + kbz + agq * 8;
  const int aldst = t * 16;

  // B staging: 2 granules/thread
  const u16* bsrc0;
  const u16* bsrc1;
  int bldst0, bldst1;
  {
    int G = t;
    int bcol = G >> 3;
    int bgq = (G & 7) ^ (bcol & 7);
    bsrc0 = Ytd + (size_t)bcol * 4096 + kbz + bgq * 8;
    bldst0 = G * 16;
    G = 512 + t;
    bcol = G >> 3;
    bgq = (G & 7) ^ (bcol & 7);
    bsrc1 = Ytd + (size_t)bcol * 4096 + kbz + bgq * 8;
    bldst1 = G * 16;
  }

  int aro, bro[4];
  {
    int row = wr * 16 + l15;
    aro = row * 128 + ((l4 ^ (row & 7)) << 4);
  }
#pragma unroll
  for (int n2 = 0; n2 < 4; ++n2) {
    int col = wc * 64 + n2 * 16 + l15;
    bro[n2] = col * 128 + ((l4 ^ (col & 7)) << 4);
  }

  f4 acc[4];
#pragma unroll
  for (int j = 0; j < 4; ++j) acc[j] = (f4){0.f, 0.f, 0.f, 0.f};

#define K2A_ISSUE(KK, BUF)                                     \
  {                                                            \
    async16(asrc + (KK) * 64, SA_BUF(BUF) + aldst);            \
    async16(bsrc0 + (KK) * 64, SB_BUF(BUF) + bldst0);          \
    async16(bsrc1 + (KK) * 64, SB_BUF(BUF) + bldst1);          \
  }
#define K2A_COMPUTE(BUF)                                                          \
  {                                                                               \
    _Pragma("unroll") for (int kk = 0; kk < 2; ++kk) {                            \
      bh8 a = *(const bh8*)(SA_BUF(BUF) + (aro ^ (kk << 6)));                     \
      _Pragma("unroll") for (int n2 = 0; n2 < 4; ++n2) {                          \
        bh8 bb = *(const bh8*)(SB_BUF(BUF) + (bro[n2] ^ (kk << 6)));              \
        acc[n2] = __builtin_amdgcn_mfma_f32_16x16x32_bf16(a, bb, acc[n2], 0, 0, 0); \
      }                                                                           \
    }                                                                             \
  }

  K2A_ISSUE(0, 0)
  K2A_ISSUE(1, 1)
  FENCE();
#pragma unroll 1
  for (int k = 0; k < 7; ++k) {
    WAITV(3);  // retire L(k) x3; L(k+1) in flight
    SBAR(); FENCE();
    K2A_COMPUTE(k & 1)
    SBAR(); FENCE();
    if (k < 6) { K2A_ISSUE(k + 2, k & 1) FENCE(); }
  }
  WAITV(0);  // retire L(7)
  SBAR(); FENCE();
  K2A_COMPUTE(1)
#undef K2A_ISSUE
#undef K2A_COMPUTE
#undef SA_BUF
#undef SB_BUF

  float* Z = Zp + (size_t)c * (N_SZ * 128) + (size_t)n0 * 128;
#pragma unroll
  for (int n2 = 0; n2 < 4; ++n2)
#pragma unroll
    for (int q = 0; q < 4; ++q) {
      int r = wr * 16 + l4 * 4 + q;
      int cc = wc * 64 + n2 * 16 + l15;
      Z[r * 128 + cc] = acc[n2][q];
    }
}

// ---------------------------------------------------------------------------
// K2b: s_dst[n][i] = s_src[n][i] + tanh(sum_c Zp[c][n][i] + b[i])  [R15-exact]
// ---------------------------------------------------------------------------
__global__ void k2b_kernel(const float* __restrict__ s_src, float* __restrict__ s_dst,
                           const float* __restrict__ Zp, const float* __restrict__ bd) {
  int idx = blockIdx.x * 256 + threadIdx.x;
  float v = bd[idx & 127];
#pragma unroll
  for (int c = 0; c < SPLITK; ++c) v += Zp[(size_t)c * (N_SZ * 128) + idx];
  s_dst[idx] = s_src[idx] + fast_tanh(v);
}

// ---------------------------------------------------------------------------
// KB1: fused k2b(depth d) + k1(depth d+1).  [R15-exact]
// ---------------------------------------------------------------------------
__global__ __launch_bounds__(256, 2) void kb1_kernel(
    const float* __restrict__ s_src, float* __restrict__ s_dst,
    const float* __restrict__ Zp, const float* __restrict__ bd,
    const float* __restrict__ Wnext, u16* __restrict__ Ytnext) {
  __shared__ float sS[16 * 132];
  __shared__ float wlds[128 * 131];
  const int t = threadIdx.x;
  const int n0 = blockIdx.x * 16;

#pragma unroll 8
  for (int j = 0; j < 64; ++j) {
    int li = j * 256 + t;
    int wr_ = li >> 7, wc_ = li & 127;
    wlds[wr_ * 131 + wc_] = Wnext[wr_ * 128 + wc_];
  }

#pragma unroll
  for (int e = 0; e < 8; ++e) {
    int idx = e * 256 + t;
    int r = idx >> 7, c = idx & 127;
    size_t gi = (size_t)(n0 + r) * 128 + c;
    float v = bd[c];
#pragma unroll
    for (int cc = 0; cc < SPLITK; ++cc) v += Zp[(size_t)cc * (N_SZ * 128) + gi];
    float res = s_src[gi] + fast_tanh(v);
    s_dst[gi] = res;
    sS[r * 132 + c] = res;
  }
  __syncthreads();

  const int i = t & 127, nh = t >> 7;
  float acc[8] = {0.f, 0.f, 0.f, 0.f, 0.f, 0.f, 0.f, 0.f};
  const float* wrow = wlds + i * 131;
#pragma unroll 4
  for (int k4 = 0; k4 < 32; ++k4) {
    float w0 = wrow[k4 * 4 + 0], w1 = wrow[k4 * 4 + 1];
    float w2 = wrow[k4 * 4 + 2], w3 = wrow[k4 * 4 + 3];
#pragma unroll
    for (int r = 0; r < 8; ++r) {
      float4 sv = *(const float4*)(sS + (nh * 8 + r) * 132 + k4 * 4);
      acc[r] = fmaf(sv.x, w0, acc[r]);
      acc[r] = fmaf(sv.y, w1, acc[r]);
      acc[r] = fmaf(sv.z, w2, acc[r]);
      acc[r] = fmaf(sv.w, w3, acc[r]);
    }
  }
  union { bh8 v; u16 u[8]; } o;
#pragma unroll
  for (int r = 0; r < 8; ++r) o.u[r] = f2bf(acc[r]);
  *(bh8*)(Ytnext + (size_t)i * 4096 + n0 + nh * 8) = o.v;
}

// ---------------------------------------------------------------------------
// phaseB v7: out = act + sum_d tanh(kern @ y_d + b_d).  [R15-exact, frozen]
// ---------------------------------------------------------------------------
__global__ __launch_bounds__(1024, 4) void pB_kernel(
    const float* __restrict__ A, const u16* __restrict__ Yt,
    const float* __restrict__ act, const float* __restrict__ bias,
    float* __restrict__ outA) {
  __shared__ char smem[16384 + 2 * 65536];
  char* sA = smem;
  char* sB0 = smem + 16384;
  char* sB1 = smem + 16384 + 65536;
  const int t = threadIdx.x, lane = t & 63, wid = t >> 6;
  const int wr = wid >> 3, wc = wid & 7;
  const int m0 = blockIdx.x * 128;
  const int l15 = lane & 15, l4 = lane >> 4;

  const int arow = t >> 3, kseg8 = t & 7;
  const float4* agp = (const float4*)(A + (size_t)(m0 + arow) * 4096 + kseg8 * 8);
  const int awoff = arow * 128 + ((kseg8 ^ (arow & 7)) << 4);

  const u16* bsrc[4];
  int bldst[4];
#pragma unroll
  for (int j = 0; j < 4; ++j) {
    int G = j * 1024 + t;
    int col = G >> 3;
    int gq = (G & 7) ^ (col & 7);
    bsrc[j] = Yt + (size_t)col * 4096 + gq * 8;
    bldst[j] = G * 16;
  }

  int aro[4], bro[4];
#pragma unroll
  for (int mf = 0; mf < 4; ++mf) {
    int row = wr * 64 + mf * 16 + l15;
    aro[mf] = row * 128 + ((l4 ^ (row & 7)) << 4);
  }
#pragma unroll
  for (int d = 0; d < 4; ++d) {
    int tc = d * 128 + wc * 16 + l15;
    bro[d] = tc * 128 + ((l4 ^ (tc & 7)) << 4);
  }

  f4 acc[4][4];
#pragma unroll
  for (int i = 0; i < 4; ++i)
#pragma unroll
    for (int j = 0; j < 4; ++j) acc[i][j] = (f4){0.f, 0.f, 0.f, 0.f};

  float4 va0 = agp[0], va1 = agp[1];
  FENCE();
#pragma unroll
  for (int j = 0; j < 4; ++j) async16(bsrc[j], sB0 + bldst[j]);
  FENCE();

  char* sBc = sB0;
  char* sBn = sB1;
#pragma unroll 1
  for (int k = 0; k < 63; ++k) {
    SBAR(); FENCE();
    WAITV(4);
    union { bh8 v; u16 u[8]; } p;
    p.u[0] = f2bf(va0.x); p.u[1] = f2bf(va0.y); p.u[2] = f2bf(va0.z); p.u[3] = f2bf(va0.w);
    p.u[4] = f2bf(va1.x); p.u[5] = f2bf(va1.y); p.u[6] = f2bf(va1.z); p.u[7] = f2bf(va1.w);
    *(bh8*)(sA + awoff) = p.v;
    FENCE();
    va0 = agp[(k + 1) * 16]; va1 = agp[(k + 1) * 16 + 1];
    FENCE();
    WAITVL(2);
    SBAR(); FENCE();
#pragma unroll
    for (int j = 0; j < 4; ++j) async16(bsrc[j] + (k + 1) * 64, sBn + bldst[j]);
    FENCE();
#pragma unroll
    for (int kk = 0; kk < 2; ++kk) {
      bh8 af[4];
#pragma unroll
      for (int mf = 0; mf < 4; ++mf) af[mf] = *(const bh8*)(sA + (aro[mf] ^ (kk << 6)));
#pragma unroll
      for (int d = 0; d < 4; ++d) {
        bh8 b = *(const bh8*)(sBc + (bro[d] ^ (kk << 6)));
#pragma unroll
        for (int mf = 0; mf < 4; ++mf)
          acc[mf][d] = __builtin_amdgcn_mfma_f32_16x16x32_bf16(af[mf], b, acc[mf][d], 0, 0, 0);
      }
    }
    char* tp = sBc; sBc = sBn; sBn = tp;
  }
  SBAR(); FENCE();
  WAITV(4);
  {
    union { bh8 v; u16 u[8]; } p;
    p.u[0] = f2bf(va0.x); p.u[1] = f2bf(va0.y); p.u[2] = f2bf(va0.z); p.u[3] = f2bf(va0.w);
    p.u[4] = f2bf(va1.x); p.u[5] = f2bf(va1.y); p.u[6] = f2bf(va1.z); p.u[7] = f2bf(va1.w);
    *(bh8*)(sA + awoff) = p.v;
  }
  WAITVL(0);
  SBAR(); FENCE();
#pragma unroll
  for (int kk = 0; kk < 2; ++kk) {
    bh8 af[4];
#pragma unroll
    for (int mf = 0; mf < 4; ++mf) af[mf] = *(const bh8*)(sA + (aro[mf] ^ (kk << 6)));
#pragma unroll
    for (int d = 0; d < 4; ++d) {
      bh8 b = *(const bh8*)(sBc + (bro[d] ^ (kk << 6)));
#pragma unroll
      for (int mf = 0; mf < 4; ++mf)
        acc[mf][d] = __builtin_amdgcn_mfma_f32_16x16x32_bf16(af[mf], b, acc[mf][d], 0, 0, 0);
    }
  }

  float bsv[4];
#pragma unroll
  for (int d = 0; d < 4; ++d) bsv[d] = bias[d * 128 + wc * 16 + l15];
#pragma unroll
  for (int mf = 0; mf < 4; ++mf)
#pragma unroll
    for (int q = 0; q < 4; ++q) {
      int r = m0 + wr * 64 + mf * 16 + l4 * 4 + q;
      int c = wc * 16 + l15;
      float s = 0.f;
#pragma unroll
      for (int d = 0; d < 4; ++d) s += fast_tanh(acc[mf][d][q] + bsv[d]);
      size_t o = (size_t)r * 128 + c;
      outA[o] = act[o] + s;
    }
}

// ---------------------------------------------------------------------------
extern "C" void kernel_launch(void* const* d_in, const int* in_sizes, int n_in,
                              void* d_out, int out_size, void* d_ws, size_t ws_size,
                              hipStream_t stream) {
  const float* act = (const float*)d_in[0];
  const float* self_act = (const float*)d_in[1];
  const float* kern = (const float*)d_in[2];
  const float* self_kern = (const float*)d_in[3];
  const float* weights = (const float*)d_in[4];
  const float* bias = (const float*)d_in[5];
  float* out = (float*)d_out;
  float* s_buf = out + (size_t)M_SZ * 128;  // self_act state lives in its output slot

  char* ws = (char*)d_ws;
  u16* Yt = (u16*)ws;                          // [512][4096] bf16, 4 MB
  float* Zp = (float*)(ws + (4u << 20));       // [SPLITK][4096][128] f32, 16 MB
  u16* SKb = (u16*)(ws + (20u << 20));         // [4096][4096] bf16, 32 MB

  // depth 0: y from self_act + one-time SK -> bf16 conversion
  k1_kernel<<<dim3(16, 16), 256, 0, stream>>>(self_act, weights, Yt, self_kern, SKb);
  for (int d = 0; d < DEPTHS; ++d) {
    const float* s_src = (d == 0) ? self_act : s_buf;
    k2a_kernel<<<dim3(64, SPLITK), 512, 0, stream>>>(SKb,
                                                     Yt + (size_t)d * 128 * 4096, Zp);
    if (d < DEPTHS - 1) {
      kb1_kernel<<<256, 256, 0, stream>>>(s_src, s_buf, Zp, bias + d * 128,
                                          weights + (d + 1) * 16384,
                                          Yt + (size_t)(d + 1) * 128 * 4096);
    } else {
      k2b_kernel<<<2048, 256, 0, stream>>>(s_src, s_buf, Zp, bias + d * 128);
    }
  }
  pB_kernel<<<256, 1024, 0, stream>>>(kern, Yt, act, bias, out);
}

// Round 18
// 307.853 us; speedup vs baseline: 2.1473x; 1.0165x over previous
//
#include <hip/hip_runtime.h>

#define M_SZ 32768
#define N_SZ 4096
#define DEPTHS 4
#define SPLITK 8
#define KCH 512  // N_SZ / SPLITK

typedef __attribute__((ext_vector_type(8))) short bh8;   // 8 bf16 (4 VGPR) MFMA frag
typedef __attribute__((ext_vector_type(4))) float f4;    // MFMA accumulator
typedef unsigned short u16;
typedef unsigned int u32;

#define SBAR() __builtin_amdgcn_s_barrier()
#define FENCE() asm volatile("" ::: "memory")
#define WAITV(n) asm volatile("s_waitcnt vmcnt(" #n ")" ::: "memory")
#define WAITVL(n) asm volatile("s_waitcnt vmcnt(" #n ") lgkmcnt(0)" ::: "memory")

__device__ __forceinline__ u16 f2bf(float f) {
  u32 u = __float_as_uint(f);
  u = (u + 0x7FFFu + ((u >> 16) & 1u)) >> 16;  // RNE
  return (u16)u;
}

__device__ __forceinline__ float fast_tanh(float x) {
  float ax = __builtin_fabsf(x);
  float e = __builtin_exp2f(ax * 2.8853900817779268f);  // e^(2|x|)
  float r = 1.0f - 2.0f * __builtin_amdgcn_rcpf(e + 1.0f);
  return __builtin_copysignf(r, x);
}

__device__ __forceinline__ void async16(const void* g, void* l) {
  __builtin_amdgcn_global_load_lds((const __attribute__((address_space(1))) u32*)g,
                                   (__attribute__((address_space(3))) u32*)l, 16, 0, 0);
}

// ---------------------------------------------------------------------------
// K1c: y_0[i][n] = sum_k s[n][k] * W0[i][k]  (transposed bf16)  [R17-exact]
// + fused one-time SK f32 -> bf16 conversion.
// ---------------------------------------------------------------------------
__global__ void k1_kernel(const float* __restrict__ s, const float* __restrict__ Wd,
                          u16* __restrict__ Ytd, const float* __restrict__ SK,
                          u16* __restrict__ SKb) {
  const int t = threadIdx.x;
  const int n = blockIdx.x * 256 + t;
  const int i0 = blockIdx.y * 8;
  float acc[8] = {0.f, 0.f, 0.f, 0.f, 0.f, 0.f, 0.f, 0.f};
  const float4* srow = (const float4*)(s + (size_t)n * 128);
#pragma unroll 4
  for (int k4 = 0; k4 < 32; ++k4) {
    float4 sv = srow[k4];
#pragma unroll
    for (int ii = 0; ii < 8; ++ii) {
      const float* w = Wd + (i0 + ii) * 128 + k4 * 4;
      acc[ii] = fmaf(sv.x, w[0], acc[ii]);
      acc[ii] = fmaf(sv.y, w[1], acc[ii]);
      acc[ii] = fmaf(sv.z, w[2], acc[ii]);
      acc[ii] = fmaf(sv.w, w[3], acc[ii]);
    }
  }
#pragma unroll
  for (int ii = 0; ii < 8; ++ii)
    Ytd[(size_t)(i0 + ii) * 4096 + n] = f2bf(acc[ii]);

  const size_t cbase = ((size_t)blockIdx.y * 16 + blockIdx.x) * 65536;
#pragma unroll 4
  for (int cc = 0; cc < 32; ++cc) {
    size_t off = cbase + (size_t)cc * 2048 + (size_t)t * 8;
    float4 u0 = *(const float4*)(SK + off);
    float4 u1 = *(const float4*)(SK + off + 4);
    union { bh8 v; u16 u[8]; } pk;
    pk.u[0] = f2bf(u0.x); pk.u[1] = f2bf(u0.y); pk.u[2] = f2bf(u0.z); pk.u[3] = f2bf(u0.w);
    pk.u[4] = f2bf(u1.x); pk.u[5] = f2bf(u1.y); pk.u[6] = f2bf(u1.z); pk.u[7] = f2bf(u1.w);
    *(bh8*)(SKb + off) = pk.v;
  }
}

// ---------------------------------------------------------------------------
// K2a v4: split-K partials of SKb(bf16) @ y_d.  [R17-exact]
// ---------------------------------------------------------------------------
__global__ __launch_bounds__(512, 4) void k2a_kernel(
    const u16* __restrict__ SKb, const u16* __restrict__ Ytd, float* __restrict__ Zp) {
  __shared__ char smem[2 * 8192 + 2 * 16384];
#define SA_BUF(BUF) (smem + (BUF) * 8192)
#define SB_BUF(BUF) (smem + 16384 + (BUF) * 16384)
  const int t = threadIdx.x, lane = t & 63, wid = t >> 6;
  const int nb = blockIdx.x, c = blockIdx.y;
  const int n0 = nb * 64;
  const int kbz = c * KCH;
  const int wr = wid >> 1, wc = wid & 1;
  const int l15 = lane & 15, l4 = lane >> 4;

  const int arow_g = t >> 3, aseg = t & 7;
  const int agq = aseg ^ (arow_g & 7);
  const u16* asrc = SKb + (size_t)(n0 + arow_g) * 4096 + kbz + agq * 8;
  const int aldst = t * 16;

  const u16* bsrc0;
  const u16* bsrc1;
  int bldst0, bldst1;
  {
    int G = t;
    int bcol = G >> 3;
    int bgq = (G & 7) ^ (bcol & 7);
    bsrc0 = Ytd + (size_t)bcol * 4096 + kbz + bgq * 8;
    bldst0 = G * 16;
    G = 512 + t;
    bcol = G >> 3;
    bgq = (G & 7) ^ (bcol & 7);
    bsrc1 = Ytd + (size_t)bcol * 4096 + kbz + bgq * 8;
    bldst1 = G * 16;
  }

  int aro, bro[4];
  {
    int row = wr * 16 + l15;
    aro = row * 128 + ((l4 ^ (row & 7)) << 4);
  }
#pragma unroll
  for (int n2 = 0; n2 < 4; ++n2) {
    int col = wc * 64 + n2 * 16 + l15;
    bro[n2] = col * 128 + ((l4 ^ (col & 7)) << 4);
  }

  f4 acc[4];
#pragma unroll
  for (int j = 0; j < 4; ++j) acc[j] = (f4){0.f, 0.f, 0.f, 0.f};

#define K2A_ISSUE(KK, BUF)                                     \
  {                                                            \
    async16(asrc + (KK) * 64, SA_BUF(BUF) + aldst);            \
    async16(bsrc0 + (KK) * 64, SB_BUF(BUF) + bldst0);          \
    async16(bsrc1 + (KK) * 64, SB_BUF(BUF) + bldst1);          \
  }
#define K2A_COMPUTE(BUF)                                                          \
  {                                                                               \
    _Pragma("unroll") for (int kk = 0; kk < 2; ++kk) {                            \
      bh8 a = *(const bh8*)(SA_BUF(BUF) + (aro ^ (kk << 6)));                     \
      _Pragma("unroll") for (int n2 = 0; n2 < 4; ++n2) {                          \
        bh8 bb = *(const bh8*)(SB_BUF(BUF) + (bro[n2] ^ (kk << 6)));              \
        acc[n2] = __builtin_amdgcn_mfma_f32_16x16x32_bf16(a, bb, acc[n2], 0, 0, 0); \
      }                                                                           \
    }                                                                             \
  }

  K2A_ISSUE(0, 0)
  K2A_ISSUE(1, 1)
  FENCE();
#pragma unroll 1
  for (int k = 0; k < 7; ++k) {
    WAITV(3);  // retire L(k) x3; L(k+1) in flight
    SBAR(); FENCE();
    K2A_COMPUTE(k & 1)
    SBAR(); FENCE();
    if (k < 6) { K2A_ISSUE(k + 2, k & 1) FENCE(); }
  }
  WAITV(0);  // retire L(7)
  SBAR(); FENCE();
  K2A_COMPUTE(1)
#undef K2A_ISSUE
#undef K2A_COMPUTE
#undef SA_BUF
#undef SB_BUF

  float* Z = Zp + (size_t)c * (N_SZ * 128) + (size_t)n0 * 128;
#pragma unroll
  for (int n2 = 0; n2 < 4; ++n2)
#pragma unroll
    for (int q = 0; q < 4; ++q) {
      int r = wr * 16 + l4 * 4 + q;
      int cc = wc * 64 + n2 * 16 + l15;
      Z[r * 128 + cc] = acc[n2][q];
    }
}

// ---------------------------------------------------------------------------
// KB1: fused k2b(depth d) + k1(depth d+1).  [R17-exact]
// ---------------------------------------------------------------------------
__global__ __launch_bounds__(256, 2) void kb1_kernel(
    const float* __restrict__ s_src, float* __restrict__ s_dst,
    const float* __restrict__ Zp, const float* __restrict__ bd,
    const float* __restrict__ Wnext, u16* __restrict__ Ytnext) {
  __shared__ float sS[16 * 132];
  __shared__ float wlds[128 * 131];
  const int t = threadIdx.x;
  const int n0 = blockIdx.x * 16;

#pragma unroll 8
  for (int j = 0; j < 64; ++j) {
    int li = j * 256 + t;
    int wr_ = li >> 7, wc_ = li & 127;
    wlds[wr_ * 131 + wc_] = Wnext[wr_ * 128 + wc_];
  }

#pragma unroll
  for (int e = 0; e < 8; ++e) {
    int idx = e * 256 + t;
    int r = idx >> 7, c = idx & 127;
    size_t gi = (size_t)(n0 + r) * 128 + c;
    float v = bd[c];
#pragma unroll
    for (int cc = 0; cc < SPLITK; ++cc) v += Zp[(size_t)cc * (N_SZ * 128) + gi];
    float res = s_src[gi] + fast_tanh(v);
    s_dst[gi] = res;
    sS[r * 132 + c] = res;
  }
  __syncthreads();

  const int i = t & 127, nh = t >> 7;
  float acc[8] = {0.f, 0.f, 0.f, 0.f, 0.f, 0.f, 0.f, 0.f};
  const float* wrow = wlds + i * 131;
#pragma unroll 4
  for (int k4 = 0; k4 < 32; ++k4) {
    float w0 = wrow[k4 * 4 + 0], w1 = wrow[k4 * 4 + 1];
    float w2 = wrow[k4 * 4 + 2], w3 = wrow[k4 * 4 + 3];
#pragma unroll
    for (int r = 0; r < 8; ++r) {
      float4 sv = *(const float4*)(sS + (nh * 8 + r) * 132 + k4 * 4);
      acc[r] = fmaf(sv.x, w0, acc[r]);
      acc[r] = fmaf(sv.y, w1, acc[r]);
      acc[r] = fmaf(sv.z, w2, acc[r]);
      acc[r] = fmaf(sv.w, w3, acc[r]);
    }
  }
  union { bh8 v; u16 u[8]; } o;
#pragma unroll
  for (int r = 0; r < 8; ++r) o.u[r] = f2bf(acc[r]);
  *(bh8*)(Ytnext + (size_t)i * 4096 + n0 + nh * 8) = o.v;
}

// ---------------------------------------------------------------------------
// phaseB v8: [R17 v7 body, frozen] + folded final-depth s-update at head
// (exact k2b math/order -> bit-identical s output; was a separate launch).
// WAITV(0) after the head retires its memory ops so the counted-vmcnt
// pipeline arithmetic stays exact.
// ---------------------------------------------------------------------------
__global__ __launch_bounds__(1024, 4) void pB_kernel(
    const float* __restrict__ A, const u16* __restrict__ Yt,
    const float* __restrict__ act, const float* __restrict__ bias,
    float* __restrict__ outA, const float* __restrict__ Zp,
    float* __restrict__ s_buf) {
  __shared__ char smem[16384 + 2 * 65536];
  char* sA = smem;
  char* sB0 = smem + 16384;
  char* sB1 = smem + 16384 + 65536;
  const int t = threadIdx.x, lane = t & 63, wid = t >> 6;
  const int wr = wid >> 3, wc = wid & 7;
  const int m0 = blockIdx.x * 128;
  const int l15 = lane & 15, l4 = lane >> 4;

  // folded final s-update (was k2b launch): s_buf += tanh(sum_c Zp + b3)
  {
    const float* b3 = bias + 3 * 128;
#pragma unroll
    for (int e = 0; e < 2; ++e) {
      int idx = blockIdx.x * 2048 + e * 1024 + t;
      float v = b3[idx & 127];
#pragma unroll
      for (int cc = 0; cc < SPLITK; ++cc) v += Zp[(size_t)cc * (N_SZ * 128) + idx];
      s_buf[idx] = s_buf[idx] + fast_tanh(v);
    }
  }
  WAITV(0);  // retire head loads/stores before the counted pipeline
  FENCE();

  const int arow = t >> 3, kseg8 = t & 7;
  const float4* agp = (const float4*)(A + (size_t)(m0 + arow) * 4096 + kseg8 * 8);
  const int awoff = arow * 128 + ((kseg8 ^ (arow & 7)) << 4);

  const u16* bsrc[4];
  int bldst[4];
#pragma unroll
  for (int j = 0; j < 4; ++j) {
    int G = j * 1024 + t;
    int col = G >> 3;
    int gq = (G & 7) ^ (col & 7);
    bsrc[j] = Yt + (size_t)col * 4096 + gq * 8;
    bldst[j] = G * 16;
  }

  int aro[4], bro[4];
#pragma unroll
  for (int mf = 0; mf < 4; ++mf) {
    int row = wr * 64 + mf * 16 + l15;
    aro[mf] = row * 128 + ((l4 ^ (row & 7)) << 4);
  }
#pragma unroll
  for (int d = 0; d < 4; ++d) {
    int tc = d * 128 + wc * 16 + l15;
    bro[d] = tc * 128 + ((l4 ^ (tc & 7)) << 4);
  }

  f4 acc[4][4];
#pragma unroll
  for (int i = 0; i < 4; ++i)
#pragma unroll
    for (int j = 0; j < 4; ++j) acc[i][j] = (f4){0.f, 0.f, 0.f, 0.f};

  float4 va0 = agp[0], va1 = agp[1];
  FENCE();
#pragma unroll
  for (int j = 0; j < 4; ++j) async16(bsrc[j], sB0 + bldst[j]);
  FENCE();

  char* sBc = sB0;
  char* sBn = sB1;
#pragma unroll 1
  for (int k = 0; k < 63; ++k) {
    SBAR(); FENCE();
    WAITV(4);
    union { bh8 v; u16 u[8]; } p;
    p.u[0] = f2bf(va0.x); p.u[1] = f2bf(va0.y); p.u[2] = f2bf(va0.z); p.u[3] = f2bf(va0.w);
    p.u[4] = f2bf(va1.x); p.u[5] = f2bf(va1.y); p.u[6] = f2bf(va1.z); p.u[7] = f2bf(va1.w);
    *(bh8*)(sA + awoff) = p.v;
    FENCE();
    va0 = agp[(k + 1) * 16]; va1 = agp[(k + 1) * 16 + 1];
    FENCE();
    WAITVL(2);
    SBAR(); FENCE();
#pragma unroll
    for (int j = 0; j < 4; ++j) async16(bsrc[j] + (k + 1) * 64, sBn + bldst[j]);
    FENCE();
#pragma unroll
    for (int kk = 0; kk < 2; ++kk) {
      bh8 af[4];
#pragma unroll
      for (int mf = 0; mf < 4; ++mf) af[mf] = *(const bh8*)(sA + (aro[mf] ^ (kk << 6)));
#pragma unroll
      for (int d = 0; d < 4; ++d) {
        bh8 b = *(const bh8*)(sBc + (bro[d] ^ (kk << 6)));
#pragma unroll
        for (int mf = 0; mf < 4; ++mf)
          acc[mf][d] = __builtin_amdgcn_mfma_f32_16x16x32_bf16(af[mf], b, acc[mf][d], 0, 0, 0);
      }
    }
    char* tp = sBc; sBc = sBn; sBn = tp;
  }
  SBAR(); FENCE();
  WAITV(4);
  {
    union { bh8 v; u16 u[8]; } p;
    p.u[0] = f2bf(va0.x); p.u[1] = f2bf(va0.y); p.u[2] = f2bf(va0.z); p.u[3] = f2bf(va0.w);
    p.u[4] = f2bf(va1.x); p.u[5] = f2bf(va1.y); p.u[6] = f2bf(va1.z); p.u[7] = f2bf(va1.w);
    *(bh8*)(sA + awoff) = p.v;
  }
  WAITVL(0);
  SBAR(); FENCE();
#pragma unroll
  for (int kk = 0; kk < 2; ++kk) {
    bh8 af[4];
#pragma unroll
    for (int mf = 0; mf < 4; ++mf) af[mf] = *(const bh8*)(sA + (aro[mf] ^ (kk << 6)));
#pragma unroll
    for (int d = 0; d < 4; ++d) {
      bh8 b = *(const bh8*)(sBc + (bro[d] ^ (kk << 6)));
#pragma unroll
      for (int mf = 0; mf < 4; ++mf)
        acc[mf][d] = __builtin_amdgcn_mfma_f32_16x16x32_bf16(af[mf], b, acc[mf][d], 0, 0, 0);
    }
  }

  float bsv[4];
#pragma unroll
  for (int d = 0; d < 4; ++d) bsv[d] = bias[d * 128 + wc * 16 + l15];
#pragma unroll
  for (int mf = 0; mf < 4; ++mf)
#pragma unroll
    for (int q = 0; q < 4; ++q) {
      int r = m0 + wr * 64 + mf * 16 + l4 * 4 + q;
      int c = wc * 16 + l15;
      float s = 0.f;
#pragma unroll
      for (int d = 0; d < 4; ++d) s += fast_tanh(acc[mf][d][q] + bsv[d]);
      size_t o = (size_t)r * 128 + c;
      outA[o] = act[o] + s;
    }
}

// ---------------------------------------------------------------------------
extern "C" void kernel_launch(void* const* d_in, const int* in_sizes, int n_in,
                              void* d_out, int out_size, void* d_ws, size_t ws_size,
                              hipStream_t stream) {
  const float* act = (const float*)d_in[0];
  const float* self_act = (const float*)d_in[1];
  const float* kern = (const float*)d_in[2];
  const float* self_kern = (const float*)d_in[3];
  const float* weights = (const float*)d_in[4];
  const float* bias = (const float*)d_in[5];
  float* out = (float*)d_out;
  float* s_buf = out + (size_t)M_SZ * 128;  // self_act state lives in its output slot

  char* ws = (char*)d_ws;
  u16* Yt = (u16*)ws;                          // [512][4096] bf16, 4 MB
  float* Zp = (float*)(ws + (4u << 20));       // [SPLITK][4096][128] f32, 16 MB
  u16* SKb = (u16*)(ws + (20u << 20));         // [4096][4096] bf16, 32 MB

  // depth 0: y from self_act + one-time SK -> bf16 conversion
  k1_kernel<<<dim3(16, 16), 256, 0, stream>>>(self_act, weights, Yt, self_kern, SKb);
  for (int d = 0; d < DEPTHS; ++d) {
    const float* s_src = (d == 0) ? self_act : s_buf;
    k2a_kernel<<<dim3(64, SPLITK), 512, 0, stream>>>(SKb,
                                                     Yt + (size_t)d * 128 * 4096, Zp);
    if (d < DEPTHS - 1) {
      kb1_kernel<<<256, 256, 0, stream>>>(s_src, s_buf, Zp, bias + d * 128,
                                          weights + (d + 1) * 16384,
                                          Yt + (size_t)(d + 1) * 128 * 4096);
    }
    // d == DEPTHS-1: final s-update folded into pB head
  }
  pB_kernel<<<256, 1024, 0, stream>>>(kern, Yt, act, bias, out, Zp, s_buf);
}